// Round 1
// baseline (1832.677 us; speedup 1.0000x reference)
//
#include <hip/hip_runtime.h>
#include <hip/hip_bf16.h>
#include <string.h>

#define F 128
#define NRAD 6
#define NSPH 42
#define NBIL 8

typedef __attribute__((ext_vector_type(8))) short bf16x8;
typedef __attribute__((ext_vector_type(4))) float f32x4;

__device__ __forceinline__ float bflo(unsigned int v){ return __uint_as_float(v << 16); }
__device__ __forceinline__ float bfhi(unsigned int v){ return __uint_as_float(v & 0xFFFF0000u); }
__device__ __forceinline__ unsigned short f2bf(float f){
  unsigned int u = __float_as_uint(f);
  return (unsigned short)((u + 0x7FFFu + ((u >> 16) & 1u)) >> 16);
}
__device__ __forceinline__ float bf2f(unsigned short u){ return __uint_as_float(((unsigned int)u) << 16); }
__device__ __forceinline__ unsigned int pack2bf(float a, float b){
  return (unsigned int)f2bf(a) | ((unsigned int)f2bf(b) << 16);
}
__device__ __forceinline__ float swishf(float x){ return x / (1.f + __expf(-x)); }

// ---------------- CSR build ----------------
__global__ void hist_kernel(const int* __restrict__ id_ji, int* __restrict__ counts, int T){
  for (int i = blockIdx.x*blockDim.x + threadIdx.x; i < T; i += gridDim.x*blockDim.x)
    atomicAdd(&counts[id_ji[i]], 1);
}

__global__ __launch_bounds__(1024) void scan_kernel(const int* __restrict__ counts,
    int* __restrict__ offs, int* __restrict__ cursor, int E, int T){
  __shared__ int part[1024];
  __shared__ int scanp[1024];
  int tid = threadIdx.x;
  int chunk = (E + 1023) / 1024;
  int b = tid*chunk, e2 = min(E, b + chunk);
  int s = 0;
  for (int i = b; i < e2; ++i) s += counts[i];
  part[tid] = s;
  __syncthreads();
  if (tid == 0){ int run = 0; for (int i = 0; i < 1024; ++i){ scanp[i] = run; run += part[i]; } }
  __syncthreads();
  int base = scanp[tid];
  for (int i = b; i < e2; ++i){ offs[i] = base; cursor[i] = base; base += counts[i]; }
  if (tid == 0) offs[E] = T;
}

__global__ void fill_kernel(const int* __restrict__ id_ji, int* __restrict__ cursor,
                            int* __restrict__ perm, int T){
  for (int i = blockIdx.x*blockDim.x + threadIdx.x; i < T; i += gridDim.x*blockDim.x){
    int pos = atomicAdd(&cursor[id_ji[i]], 1);
    perm[pos] = i;
  }
}

// ---------------- weight prep ----------------
struct Ptrs9 { const float* p[9]; };

// dst[i] layout: Bt[n][k] = W[k][n], bf16, 128x128 each
__global__ void prep_w_kernel(Ptrs9 ps, unsigned short* __restrict__ dst){
  int i = blockIdx.y;
  const float* src = ps.p[i];
  int idx = blockIdx.x*256 + threadIdx.x;     // 0..16383
  int n = idx & 127, k = idx >> 7;
  dst[i*16384 + n*128 + k] = f2bf(src[k*128 + n]);
}

// WtB[n][l] = bilin[i][j][l], n = j*128+i  (Bt layout for Y gemm, N=1024, K=128)
__global__ void prep_bilin_kernel(const float* __restrict__ bilin, unsigned short* __restrict__ dst){
  int t = blockIdx.x*256 + threadIdx.x;       // 0..131071
  int n = t >> 7, l = t & 127;
  int i = n & 127, j = n >> 7;
  dst[t] = f2bf(bilin[(size_t)i*1024 + j*128 + l]);
}

__global__ void prep_ml_kernel(const float* __restrict__ src, unsigned short* __restrict__ dst, int n4){
  int i = blockIdx.x*256 + threadIdx.x;
  if (i >= n4) return;
  float4 v = ((const float4*)src)[i];
  uint2 o;
  o.x = pack2bf(v.x, v.y);
  o.y = pack2bf(v.z, v.w);
  ((uint2*)dst)[i] = o;
}

// gate[e][i] = e_rbf[e] @ W_rbf  (bf16)
__global__ void gate_kernel(const float* __restrict__ e_rbf, const float* __restrict__ W_rbf,
                            unsigned short* __restrict__ gate, int E){
  int idx = blockIdx.x*256 + threadIdx.x;
  if (idx >= E*F) return;
  int e = idx >> 7, i = idx & 127;
  float s = 0.f;
  #pragma unroll
  for (int r = 0; r < NRAD; ++r) s += e_rbf[e*NRAD + r] * W_rbf[r*F + i];
  gate[idx] = f2bf(s);
}

// a8[w][j] = a_sbf[w] @ W_sbf  (bf16 [T][8])
__global__ __launch_bounds__(256) void a_pre_kernel(const float* __restrict__ a_sbf,
    const float* __restrict__ W_sbf, unsigned short* __restrict__ a8, int T){
  __shared__ float tile[256*45];
  __shared__ float wsh[NSPH*NBIL];
  int tid = threadIdx.x;
  int w0 = blockIdx.x*256;
  for (int i = tid; i < NSPH*NBIL; i += 256) wsh[i] = W_sbf[i];
  int total = 256*NSPH;
  size_t base = (size_t)w0 * NSPH;
  for (int k = tid; k < total; k += 256){
    int r = k / NSPH, c = k - r*NSPH;
    float v = 0.f;
    if (w0 + r < T) v = a_sbf[base + k];
    tile[r*45 + c] = v;
  }
  __syncthreads();
  int wI = w0 + tid;
  if (wI >= T) return;
  float out[8] = {0,0,0,0,0,0,0,0};
  for (int s = 0; s < NSPH; ++s){
    float av = tile[tid*45 + s];
    #pragma unroll
    for (int j = 0; j < 8; ++j) out[j] += av * wsh[s*8 + j];
  }
  uint4 ov;
  ov.x = pack2bf(out[0], out[1]);
  ov.y = pack2bf(out[2], out[3]);
  ov.z = pack2bf(out[4], out[5]);
  ov.w = pack2bf(out[6], out[7]);
  ((uint4*)a8)[wI] = ov;
}

// ---------------- MFMA tile GEMM: out = [addsrc +] [gate *] act(A @ B + bias) ----------------
// A: [M][128] bf16, Bt: [N][128] bf16 (pre-transposed), out cols per block = 128
__global__ __launch_bounds__(256) void gemm_tile(
    const unsigned short* __restrict__ A, const unsigned short* __restrict__ Bt,
    const float* __restrict__ bias, const unsigned short* __restrict__ gate,
    const unsigned short* __restrict__ addsrc,
    unsigned short* __restrict__ outb, float* __restrict__ outf,
    int M, int N, int do_swish){
  __shared__ unsigned short As[128][128];
  __shared__ unsigned short Bs[128][128];
  int bm = blockIdx.x, bn = blockIdx.y;
  int tid = threadIdx.x;
  int row0 = bm*128;
  #pragma unroll
  for (int it = 0; it < 8; ++it){
    int e = (tid + it*256) * 8;
    int r = e >> 7, c = e & 127;
    int cs = c ^ ((r & 7) << 3);
    uint4 va = make_uint4(0,0,0,0);
    if (row0 + r < M) va = *(const uint4*)(A + (size_t)(row0 + r)*128 + c);
    *(uint4*)(&As[r][cs]) = va;
    uint4 vb = *(const uint4*)(Bt + (size_t)(bn*128 + r)*128 + c);
    *(uint4*)(&Bs[r][cs]) = vb;
  }
  __syncthreads();
  int wid = tid >> 6, lane = tid & 63;
  int wr = (wid >> 1) * 64, wc = (wid & 1) * 64;
  int lrow = lane & 15, lk = (lane >> 4) * 8;
  f32x4 acc[4][4] = {};
  #pragma unroll
  for (int k = 0; k < 4; ++k){
    bf16x8 af[4], bfr[4];
    #pragma unroll
    for (int m = 0; m < 4; ++m){
      int r = wr + m*16 + lrow;
      int c = (k*32 + lk) ^ ((r & 7) << 3);
      af[m] = *(const bf16x8*)(&As[r][c]);
    }
    #pragma unroll
    for (int n = 0; n < 4; ++n){
      int r = wc + n*16 + lrow;
      int c = (k*32 + lk) ^ ((r & 7) << 3);
      bfr[n] = *(const bf16x8*)(&Bs[r][c]);
    }
    #pragma unroll
    for (int m = 0; m < 4; ++m)
      #pragma unroll
      for (int n = 0; n < 4; ++n)
        acc[m][n] = __builtin_amdgcn_mfma_f32_16x16x32_bf16(af[m], bfr[n], acc[m][n], 0, 0, 0);
  }
  int drow0 = (lane >> 4) * 4;
  int dcol  = lane & 15;
  #pragma unroll
  for (int m = 0; m < 4; ++m){
    #pragma unroll
    for (int n = 0; n < 4; ++n){
      int gcol = bn*128 + wc + n*16 + dcol;
      float bv = bias ? bias[gcol] : 0.f;
      #pragma unroll
      for (int r = 0; r < 4; ++r){
        int grow = row0 + wr + m*16 + drow0 + r;
        if (grow >= M) continue;
        float v = acc[m][n][r] + bv;
        if (do_swish) v = swishf(v);
        size_t oidx = (size_t)grow * N + gcol;
        if (gate)   v *= bf2f(gate[oidx]);
        if (addsrc) v += bf2f(addsrc[oidx]);
        if (outb) outb[oidx] = f2bf(v);
        if (outf) outf[oidx] = v;
      }
    }
  }
}

// ---------------- stage 2: per-edge gather-reduce over triplets ----------------
// h0[e] = m_ji[e] + sum_{w in N(e)} sum_j a8[w][j] * Y[id_kj[w]][j][:]
__global__ __launch_bounds__(256) void stage2_kernel(
    const int* __restrict__ offs, const int* __restrict__ perm, const int* __restrict__ id_kj,
    const unsigned short* __restrict__ a8, const unsigned short* __restrict__ Y,
    const unsigned short* __restrict__ m_ji, unsigned short* __restrict__ h0, int E){
  int wid = threadIdx.x >> 6, lane = threadIdx.x & 63;
  int e = blockIdx.x * 4 + wid;
  if (e >= E) return;
  float ax = 0.f, ay = 0.f;
  int beg = offs[e], end = offs[e+1];
  for (int idx = beg; idx < end; ++idx){
    int w = perm[idx];
    int kj = id_kj[w];
    uint4 av = *(const uint4*)(a8 + (size_t)w*8);
    float a0 = bflo(av.x), a1 = bfhi(av.x);
    float a2 = bflo(av.y), a3 = bfhi(av.y);
    float a4 = bflo(av.z), a5 = bfhi(av.z);
    float a6 = bflo(av.w), a7 = bfhi(av.w);
    const unsigned int* yrow = (const unsigned int*)(Y + (size_t)kj*1024);
    unsigned int v;
    v = yrow[0*64 + lane]; ax += a0*bflo(v); ay += a0*bfhi(v);
    v = yrow[1*64 + lane]; ax += a1*bflo(v); ay += a1*bfhi(v);
    v = yrow[2*64 + lane]; ax += a2*bflo(v); ay += a2*bfhi(v);
    v = yrow[3*64 + lane]; ax += a3*bflo(v); ay += a3*bfhi(v);
    v = yrow[4*64 + lane]; ax += a4*bflo(v); ay += a4*bfhi(v);
    v = yrow[5*64 + lane]; ax += a5*bflo(v); ay += a5*bfhi(v);
    v = yrow[6*64 + lane]; ax += a6*bflo(v); ay += a6*bfhi(v);
    v = yrow[7*64 + lane]; ax += a7*bflo(v); ay += a7*bfhi(v);
  }
  unsigned int mj = ((const unsigned int*)m_ji)[(size_t)e*64 + lane];
  ax += bflo(mj);
  ay += bfhi(mj);
  ((unsigned int*)h0)[(size_t)e*64 + lane] = pack2bf(ax, ay);
}

// ---------------- host ----------------
static void launch_gemm(const unsigned short* A, const unsigned short* Bt, const float* bias,
    const unsigned short* gate, const unsigned short* addsrc,
    unsigned short* outb, float* outf, int M, int N, int sw, hipStream_t s){
  dim3 g((M + 127)/128, N/128);
  gemm_tile<<<g, 256, 0, s>>>(A, Bt, bias, gate, addsrc, outb, outf, M, N, sw);
}

extern "C" void kernel_launch(void* const* d_in, const int* in_sizes, int n_in,
                              void* d_out, int out_size, void* d_ws, size_t ws_size,
                              hipStream_t stream){
  const float* m_l_1 = (const float*)d_in[0];
  const float* e_rbf = (const float*)d_in[1];
  const float* a_sbf = (const float*)d_in[2];
  const int* id_kj   = (const int*)d_in[3];
  const int* id_ji   = (const int*)d_in[4];
  const float* W_rbf = (const float*)d_in[5];
  const float* W_sbf = (const float*)d_in[6];
  const float* W_ji  = (const float*)d_in[7];
  const float* b_ji  = (const float*)d_in[8];
  const float* W_kj  = (const float*)d_in[9];
  const float* b_kj  = (const float*)d_in[10];
  const float* bilin = (const float*)d_in[11];
  const float* W_bs  = (const float*)d_in[12];
  const float* b_bs  = (const float*)d_in[13];
  const float* r1_W1 = (const float*)d_in[14]; const float* r1_b1 = (const float*)d_in[15];
  const float* r1_W2 = (const float*)d_in[16]; const float* r1_b2 = (const float*)d_in[17];
  const float* r3_W1 = (const float*)d_in[18]; const float* r3_b1 = (const float*)d_in[19];
  const float* r3_W2 = (const float*)d_in[20]; const float* r3_b2 = (const float*)d_in[21];
  const float* r4_W1 = (const float*)d_in[22]; const float* r4_b1 = (const float*)d_in[23];
  const float* r4_W2 = (const float*)d_in[24]; const float* r4_b2 = (const float*)d_in[25];

  const int E = in_sizes[0] / F;
  const int T = in_sizes[3];

  char* ws = (char*)d_ws;
  size_t off = 0;
  auto alloc = [&](size_t b)->char*{
    char* p = ws + off;
    off = (off + b + 255) & ~(size_t)255;
    return p;
  };
  unsigned short* Y    = (unsigned short*)alloc((size_t)E*1024*2);
  unsigned short* P0   = (unsigned short*)alloc((size_t)E*F*2);
  unsigned short* P1   = (unsigned short*)alloc((size_t)E*F*2);
  unsigned short* P2   = (unsigned short*)alloc((size_t)E*F*2);
  unsigned short* P3   = (unsigned short*)alloc((size_t)E*F*2);
  unsigned short* mlbf = (unsigned short*)alloc((size_t)E*F*2);
  unsigned short* a8   = (unsigned short*)alloc((size_t)T*8*2);
  int* perm   = (int*)alloc((size_t)T*4);
  int* counts = (int*)alloc((size_t)E*4);
  int* offs   = (int*)alloc((size_t)(E+1)*4);
  int* cursor = (int*)alloc((size_t)E*4);
  unsigned short* Wbt = (unsigned short*)alloc((size_t)9*16384*2);
  unsigned short* WtB = (unsigned short*)alloc((size_t)131072*2);
  if (off > ws_size) return;   // ws too small: bail (will fail check, not corrupt)

  // CSR build for id_ji
  hipMemsetAsync(counts, 0, (size_t)E*4, stream);
  hist_kernel<<<2048, 256, 0, stream>>>(id_ji, counts, T);
  scan_kernel<<<1, 1024, 0, stream>>>(counts, offs, cursor, E, T);
  fill_kernel<<<2048, 256, 0, stream>>>(id_ji, cursor, perm, T);

  // weight / input preps
  Ptrs9 p9;
  p9.p[0] = W_ji;  p9.p[1] = W_kj;  p9.p[2] = r1_W1; p9.p[3] = r1_W2; p9.p[4] = W_bs;
  p9.p[5] = r3_W1; p9.p[6] = r3_W2; p9.p[7] = r4_W1; p9.p[8] = r4_W2;
  prep_w_kernel<<<dim3(64, 9), 256, 0, stream>>>(p9, Wbt);
  prep_bilin_kernel<<<512, 256, 0, stream>>>(bilin, WtB);
  prep_ml_kernel<<<(E*F/4 + 255)/256, 256, 0, stream>>>(m_l_1, mlbf, E*F/4);
  gate_kernel<<<(E*F + 255)/256, 256, 0, stream>>>(e_rbf, W_rbf, P2, E);
  a_pre_kernel<<<(T + 255)/256, 256, 0, stream>>>(a_sbf, W_sbf, a8, T);

  // m_ji = swish(ml @ W_ji + b_ji)            -> P0
  launch_gemm(mlbf, Wbt + 0*16384, b_ji, nullptr, nullptr, P0, nullptr, E, F, 1, stream);
  // m_kj = swish(ml @ W_kj + b_kj) * gate(P2) -> P1
  launch_gemm(mlbf, Wbt + 1*16384, b_kj, P2, nullptr, P1, nullptr, E, F, 1, stream);
  // Y = m_kj @ bilin^T  [E,1024]              -> Y
  launch_gemm(P1, WtB, nullptr, nullptr, nullptr, Y, nullptr, E, 1024, 0, stream);
  // h0 = m_ji + scatter(x)                    -> P2
  stage2_kernel<<<(E + 3)/4, 256, 0, stream>>>(offs, perm, id_kj, a8, Y, P0, P2, E);
  // h1 = swish(h0 @ r1W1 + b)                 -> P1
  launch_gemm(P2, Wbt + 2*16384, r1_b1, nullptr, nullptr, P1, nullptr, E, F, 1, stream);
  // h2 = h0 + swish(h1 @ r1W2 + b)            -> P3
  launch_gemm(P1, Wbt + 3*16384, r1_b2, nullptr, P2, P3, nullptr, E, F, 1, stream);
  // h3 = swish(h2 @ Wbs + b) + m_l_1          -> P0
  launch_gemm(P3, Wbt + 4*16384, b_bs, nullptr, mlbf, P0, nullptr, E, F, 1, stream);
  // h4 = swish(h3 @ r3W1 + b)                 -> P1
  launch_gemm(P0, Wbt + 5*16384, r3_b1, nullptr, nullptr, P1, nullptr, E, F, 1, stream);
  // h5 = h3 + swish(h4 @ r3W2 + b)            -> P2
  launch_gemm(P1, Wbt + 6*16384, r3_b2, nullptr, P0, P2, nullptr, E, F, 1, stream);
  // h6 = swish(h5 @ r4W1 + b)                 -> P1
  launch_gemm(P2, Wbt + 7*16384, r4_b1, nullptr, nullptr, P1, nullptr, E, F, 1, stream);
  // out = h5 + swish(h6 @ r4W2 + b)           -> d_out (f32)
  launch_gemm(P1, Wbt + 8*16384, r4_b2, nullptr, P2, nullptr, (float*)d_out, E, F, 1, stream);
}

// Round 3
// 1365.658 us; speedup vs baseline: 1.3420x; 1.3420x over previous
//
#include <hip/hip_runtime.h>
#include <hip/hip_bf16.h>

#define F 128
#define NRAD 6
#define NSPH 42

typedef __attribute__((ext_vector_type(8))) short bf16x8;
typedef __attribute__((ext_vector_type(4))) float f32x4;

__device__ __forceinline__ float bflo(unsigned int v){ return __uint_as_float(v << 16); }
__device__ __forceinline__ float bfhi(unsigned int v){ return __uint_as_float(v & 0xFFFF0000u); }
__device__ __forceinline__ unsigned short f2bf(float f){
  unsigned int u = __float_as_uint(f);
  return (unsigned short)((u + 0x7FFFu + ((u >> 16) & 1u)) >> 16);
}
__device__ __forceinline__ float bf2f(unsigned short u){ return __uint_as_float(((unsigned int)u) << 16); }
__device__ __forceinline__ unsigned int pack2bf(float a, float b){
  return (unsigned int)f2bf(a) | ((unsigned int)f2bf(b) << 16);
}
__device__ __forceinline__ float swishf(float x){ return x / (1.f + __expf(-x)); }

// ---------------- CSR build ----------------
__global__ void hist_kernel(const int* __restrict__ id_ji, int* __restrict__ counts, int T){
  for (int i = blockIdx.x*blockDim.x + threadIdx.x; i < T; i += gridDim.x*blockDim.x)
    atomicAdd(&counts[id_ji[i]], 1);
}

__global__ __launch_bounds__(1024) void scan_kernel(const int* __restrict__ counts,
    int* __restrict__ offs, int* __restrict__ cursor, int E, int T){
  __shared__ int part[1024];
  __shared__ int scanp[1024];
  int tid = threadIdx.x;
  int chunk = (E + 1023) / 1024;
  int b = tid*chunk, e2 = min(E, b + chunk);
  int s = 0;
  for (int i = b; i < e2; ++i) s += counts[i];
  part[tid] = s;
  __syncthreads();
  if (tid == 0){ int run = 0; for (int i = 0; i < 1024; ++i){ scanp[i] = run; run += part[i]; } }
  __syncthreads();
  int base = scanp[tid];
  for (int i = b; i < e2; ++i){ offs[i] = base; cursor[i] = base; base += counts[i]; }
  if (tid == 0) offs[E] = T;
}

// fill: pkj[pos] = id_kj[i]; ppos[i] = pos (inverse perm for a_pre scatter)
__global__ void fill_kernel(const int* __restrict__ id_ji, const int* __restrict__ id_kj,
                            int* __restrict__ cursor, int* __restrict__ pkj,
                            int* __restrict__ ppos, int T){
  for (int i = blockIdx.x*blockDim.x + threadIdx.x; i < T; i += gridDim.x*blockDim.x){
    int pos = atomicAdd(&cursor[id_ji[i]], 1);
    pkj[pos] = id_kj[i];
    ppos[i] = pos;
  }
}

// ---------------- weight prep (pre-swizzled LDS-image layouts) ----------------
struct Ptrs9 { const float* p[9]; };

// Bt[n][k] = W[k][n], stored as swizzled image: dst[n*128 + (k ^ ((n&7)<<3))]
__global__ void prep_w_kernel(Ptrs9 ps, unsigned short* __restrict__ dst){
  int i = blockIdx.y;
  const float* src = ps.p[i];
  int idx = blockIdx.x*256 + threadIdx.x;     // 0..16383
  int n = idx >> 7, k = idx & 127;
  dst[i*16384 + n*128 + (k ^ ((n & 7) << 3))] = f2bf(src[k*128 + n]);
}

// WtB image: row n = j*128+i (tile j, within-tile row i), col l; value bilin[i][j][l]
__global__ void prep_bilin_kernel(const float* __restrict__ bilin, unsigned short* __restrict__ dst){
  int t = blockIdx.x*256 + threadIdx.x;       // 0..131071
  int n = t >> 7, l = t & 127;
  int i = n & 127, j = n >> 7;
  int r = n & 127;
  dst[(size_t)n*128 + (l ^ ((r & 7) << 3))] = f2bf(bilin[(size_t)i*1024 + j*128 + l]);
}

// a8 = a_sbf @ W_sbf, scattered directly into perm order via ppos
__global__ __launch_bounds__(256) void a_pre_kernel(const float* __restrict__ a_sbf,
    const float* __restrict__ W_sbf, const int* __restrict__ ppos,
    uint4* __restrict__ apg, int T){
  __shared__ float tile[256*45];
  __shared__ float wsh[NSPH*8];
  int tid = threadIdx.x;
  int w0 = blockIdx.x*256;
  for (int i = tid; i < NSPH*8; i += 256) wsh[i] = W_sbf[i];
  int total = 256*NSPH;
  size_t base = (size_t)w0 * NSPH;
  for (int k = tid; k < total; k += 256){
    int r = k / NSPH, c = k - r*NSPH;
    float v = 0.f;
    if (w0 + r < T) v = a_sbf[base + k];
    tile[r*45 + c] = v;
  }
  __syncthreads();
  int wI = w0 + tid;
  if (wI >= T) return;
  float out[8] = {0,0,0,0,0,0,0,0};
  for (int s = 0; s < NSPH; ++s){
    float av = tile[tid*45 + s];
    #pragma unroll
    for (int j = 0; j < 8; ++j) out[j] += av * wsh[s*8 + j];
  }
  uint4 ov;
  ov.x = pack2bf(out[0], out[1]);
  ov.y = pack2bf(out[2], out[3]);
  ov.z = pack2bf(out[4], out[5]);
  ov.w = pack2bf(out[6], out[7]);
  apg[ppos[wI]] = ov;
}

// ---------------- shared MFMA helpers ----------------
__device__ __forceinline__ void mfma_kloop(
    const unsigned short (*As)[128], const unsigned short (*Ws)[128],
    int wr, int wc, int lrow, int lk, f32x4 acc[4][4]){
  #pragma unroll
  for (int m = 0; m < 4; ++m)
    #pragma unroll
    for (int n = 0; n < 4; ++n)
      acc[m][n] = (f32x4){0.f,0.f,0.f,0.f};
  #pragma unroll
  for (int k = 0; k < 4; ++k){
    bf16x8 af[4], bf[4];
    #pragma unroll
    for (int m = 0; m < 4; ++m){
      int r = wr + m*16 + lrow;
      int c = (k*32 + lk) ^ ((r & 7) << 3);
      af[m] = *(const bf16x8*)(&As[r][c]);
    }
    #pragma unroll
    for (int n = 0; n < 4; ++n){
      int r = wc + n*16 + lrow;
      int c = (k*32 + lk) ^ ((r & 7) << 3);
      bf[n] = *(const bf16x8*)(&Ws[r][c]);
    }
    #pragma unroll
    for (int m = 0; m < 4; ++m)
      #pragma unroll
      for (int n = 0; n < 4; ++n)
        acc[m][n] = __builtin_amdgcn_mfma_f32_16x16x32_bf16(af[m], bf[n], acc[m][n], 0, 0, 0);
  }
}

// ---------------- head: m_ji, m_kj (gated), mlbf in one pass ----------------
__global__ __launch_bounds__(256) void head_kernel(
    const float* __restrict__ A, const unsigned short* __restrict__ Wji,
    const unsigned short* __restrict__ Wkj,
    const float* __restrict__ b_ji, const float* __restrict__ b_kj,
    const float* __restrict__ e_rbf, const float* __restrict__ W_rbf,
    unsigned short* __restrict__ m_ji, unsigned short* __restrict__ m_kj,
    unsigned short* __restrict__ mlbf, int E){
  __shared__ unsigned short Hs[128][128];
  __shared__ unsigned short W1s[128][128];
  __shared__ unsigned short W2s[128][128];
  int tid = threadIdx.x;
  int row0 = blockIdx.x * 128;
  #pragma unroll
  for (int it = 0; it < 16; ++it){
    int lin = tid + it*256;
    int r = lin >> 5;
    int c = (lin & 31) * 4;
    float4 v = make_float4(0.f,0.f,0.f,0.f);
    bool ok = (row0 + r < E);
    if (ok) v = *(const float4*)(A + (size_t)(row0 + r)*128 + c);
    uint2 o; o.x = pack2bf(v.x, v.y); o.y = pack2bf(v.z, v.w);
    int cs = c ^ ((r & 7) << 3);
    *(uint2*)(&Hs[r][cs]) = o;
    if (ok) *(uint2*)(mlbf + (size_t)(row0 + r)*128 + cs) = o;
  }
  #pragma unroll
  for (int it = 0; it < 8; ++it){
    int lin = tid + it*256;
    ((uint4*)W1s)[lin] = ((const uint4*)Wji)[lin];
    ((uint4*)W2s)[lin] = ((const uint4*)Wkj)[lin];
  }
  __syncthreads();
  int wid = tid >> 6, lane = tid & 63;
  int wr = (wid >> 1)*64, wc = (wid & 1)*64;
  int lrow = lane & 15, lk = (lane >> 4)*8;
  f32x4 acc1[4][4], acc2[4][4];
  #pragma unroll
  for (int m = 0; m < 4; ++m)
    #pragma unroll
    for (int n = 0; n < 4; ++n){ acc1[m][n] = (f32x4){0,0,0,0}; acc2[m][n] = (f32x4){0,0,0,0}; }
  #pragma unroll
  for (int k = 0; k < 4; ++k){
    bf16x8 af[4], b1[4], b2[4];
    #pragma unroll
    for (int m = 0; m < 4; ++m){
      int r = wr + m*16 + lrow;
      int c = (k*32 + lk) ^ ((r & 7) << 3);
      af[m] = *(const bf16x8*)(&Hs[r][c]);
    }
    #pragma unroll
    for (int n = 0; n < 4; ++n){
      int r = wc + n*16 + lrow;
      int c = (k*32 + lk) ^ ((r & 7) << 3);
      b1[n] = *(const bf16x8*)(&W1s[r][c]);
      b2[n] = *(const bf16x8*)(&W2s[r][c]);
    }
    #pragma unroll
    for (int m = 0; m < 4; ++m)
      #pragma unroll
      for (int n = 0; n < 4; ++n){
        acc1[m][n] = __builtin_amdgcn_mfma_f32_16x16x32_bf16(af[m], b1[n], acc1[m][n], 0, 0, 0);
        acc2[m][n] = __builtin_amdgcn_mfma_f32_16x16x32_bf16(af[m], b2[n], acc2[m][n], 0, 0, 0);
      }
  }
  __syncthreads();
  int drow0 = (lane >> 4)*4, dcol = lane & 15;
  // ---- m_ji = swish(acc1 + b_ji) ----
  #pragma unroll
  for (int m = 0; m < 4; ++m)
    #pragma unroll
    for (int n = 0; n < 4; ++n){
      int col = wc + n*16 + dcol;
      float bv = b_ji[col];
      #pragma unroll
      for (int q = 0; q < 4; ++q){
        int r = wr + m*16 + drow0 + q;
        Hs[r][col ^ ((r & 7) << 3)] = f2bf(swishf(acc1[m][n][q] + bv));
      }
    }
  __syncthreads();
  #pragma unroll
  for (int it = 0; it < 8; ++it){
    int lin = tid + it*256;
    int r = lin >> 4; int c = (lin & 15)*8;
    uint4 d = *(const uint4*)(&Hs[r][c ^ ((r & 7) << 3)]);
    if (row0 + r < E) *(uint4*)(m_ji + (size_t)(row0 + r)*128 + c) = d;
  }
  __syncthreads();
  // ---- m_kj = swish(acc2 + b_kj) * (e_rbf @ W_rbf), stored as swizzled image ----
  float wrb[4][6];
  #pragma unroll
  for (int n = 0; n < 4; ++n){
    int col = wc + n*16 + dcol;
    #pragma unroll
    for (int rr = 0; rr < 6; ++rr) wrb[n][rr] = W_rbf[rr*128 + col];
  }
  #pragma unroll
  for (int m = 0; m < 4; ++m){
    #pragma unroll
    for (int q = 0; q < 4; ++q){
      int grow = row0 + wr + m*16 + drow0 + q;
      int er = (grow < E) ? grow : 0;
      float e0 = e_rbf[er*6+0], e1 = e_rbf[er*6+1], e2 = e_rbf[er*6+2];
      float e3 = e_rbf[er*6+3], e4 = e_rbf[er*6+4], e5 = e_rbf[er*6+5];
      int rloc = wr + m*16 + drow0 + q;
      #pragma unroll
      for (int n = 0; n < 4; ++n){
        int col = wc + n*16 + dcol;
        float g = e0*wrb[n][0] + e1*wrb[n][1] + e2*wrb[n][2]
                + e3*wrb[n][3] + e4*wrb[n][4] + e5*wrb[n][5];
        float v = swishf(acc2[m][n][q] + b_kj[col]) * g;
        Hs[rloc][col ^ ((rloc & 7) << 3)] = f2bf(v);
      }
    }
  }
  __syncthreads();
  #pragma unroll
  for (int it = 0; it < 8; ++it){
    int lin = tid + it*256;
    int r = lin >> 4;
    if (row0 + r < E)
      ((uint4*)(m_kj + (size_t)row0*128))[lin] = ((const uint4*)Hs)[lin];
  }
}

// ---------------- Y = m_kj @ bilin^T  [Epad,1024] ----------------
__global__ __launch_bounds__(256) void ygemm_kernel(
    const unsigned short* __restrict__ Aimg, const unsigned short* __restrict__ Bimg,
    unsigned short* __restrict__ Y){
  __shared__ unsigned short As[128][128];
  __shared__ unsigned short Bs[128][128];
  int tid = threadIdx.x;
  int row0 = blockIdx.x*128, bn = blockIdx.y;
  #pragma unroll
  for (int it = 0; it < 8; ++it){
    int lin = tid + it*256;
    ((uint4*)As)[lin] = ((const uint4*)(Aimg + (size_t)row0*128))[lin];
    ((uint4*)Bs)[lin] = ((const uint4*)(Bimg + (size_t)bn*16384))[lin];
  }
  __syncthreads();
  int wid = tid >> 6, lane = tid & 63;
  int wr = (wid >> 1)*64, wc = (wid & 1)*64;
  int lrow = lane & 15, lk = (lane >> 4)*8;
  f32x4 acc[4][4];
  mfma_kloop(As, Bs, wr, wc, lrow, lk, acc);
  __syncthreads();
  int drow0 = (lane >> 4)*4, dcol = lane & 15;
  #pragma unroll
  for (int m = 0; m < 4; ++m)
    #pragma unroll
    for (int n = 0; n < 4; ++n)
      #pragma unroll
      for (int q = 0; q < 4; ++q){
        int r = wr + m*16 + drow0 + q;
        int col = wc + n*16 + dcol;
        As[r][col ^ ((r & 7) << 3)] = f2bf(acc[m][n][q]);
      }
  __syncthreads();
  #pragma unroll
  for (int it = 0; it < 8; ++it){
    int lin = tid + it*256;
    int r = lin >> 4; int c = (lin & 15)*8;
    uint4 d = *(const uint4*)(&As[r][c ^ ((r & 7) << 3)]);
    *(uint4*)(Y + (size_t)(row0 + r)*1024 + bn*128 + c) = d;
  }
}

// ---------------- stage 2: per-edge gather-reduce ----------------
__global__ __launch_bounds__(256) void stage2_kernel(
    const int* __restrict__ offs, const int* __restrict__ pkj,
    const uint4* __restrict__ apg, const unsigned short* __restrict__ Y,
    const unsigned short* __restrict__ m_ji, unsigned short* __restrict__ h0img, int E){
  int e = blockIdx.x*4 + (threadIdx.x >> 6);
  if (e >= E) return;
  int lane = threadIdx.x & 63;
  int jsel = lane >> 4;
  int beg = offs[e], end = offs[e+1];
  float acc[8] = {0,0,0,0,0,0,0,0};
  int kj = 0; uint4 av = make_uint4(0,0,0,0);
  if (beg < end){ kj = pkj[beg]; av = apg[beg]; }
  for (int idx = beg; idx < end; ++idx){
    const uint4* yrow = (const uint4*)(Y + (size_t)kj*1024);
    uint4 ya = yrow[lane];
    uint4 yb = yrow[64 + lane];
    int kjn = kj; uint4 avn = av;
    if (idx + 1 < end){ kjn = pkj[idx+1]; avn = apg[idx+1]; }
    unsigned int ulo = (jsel & 2) ? av.y : av.x;
    unsigned int uhi = (jsel & 2) ? av.w : av.z;
    float alo = (jsel & 1) ? bfhi(ulo) : bflo(ulo);
    float ahi = (jsel & 1) ? bfhi(uhi) : bflo(uhi);
    acc[0] += alo*bflo(ya.x); acc[1] += alo*bfhi(ya.x);
    acc[2] += alo*bflo(ya.y); acc[3] += alo*bfhi(ya.y);
    acc[4] += alo*bflo(ya.z); acc[5] += alo*bfhi(ya.z);
    acc[6] += alo*bflo(ya.w); acc[7] += alo*bfhi(ya.w);
    acc[0] += ahi*bflo(yb.x); acc[1] += ahi*bfhi(yb.x);
    acc[2] += ahi*bflo(yb.y); acc[3] += ahi*bfhi(yb.y);
    acc[4] += ahi*bflo(yb.z); acc[5] += ahi*bfhi(yb.z);
    acc[6] += ahi*bflo(yb.w); acc[7] += ahi*bfhi(yb.w);
    kj = kjn; av = avn;
  }
  #pragma unroll
  for (int q = 0; q < 8; ++q){
    acc[q] += __shfl_xor(acc[q], 16);
    acc[q] += __shfl_xor(acc[q], 32);
  }
  if (lane < 16){
    uint4 mj = ((const uint4*)(m_ji + (size_t)e*128))[lane];
    acc[0] += bflo(mj.x); acc[1] += bfhi(mj.x);
    acc[2] += bflo(mj.y); acc[3] += bfhi(mj.y);
    acc[4] += bflo(mj.z); acc[5] += bfhi(mj.z);
    acc[6] += bflo(mj.w); acc[7] += bfhi(mj.w);
    uint4 o;
    o.x = pack2bf(acc[0], acc[1]); o.y = pack2bf(acc[2], acc[3]);
    o.z = pack2bf(acc[4], acc[5]); o.w = pack2bf(acc[6], acc[7]);
    ((uint4*)(h0img + (size_t)e*128))[lane ^ (e & 7)] = o;   // swizzled image for chain
  }
}

// ---------------- fused residual chain: 7 GEMMs, state in LDS ----------------
struct Bias7 { const float* p[7]; };

__global__ __launch_bounds__(256) void chain_kernel(
    const unsigned short* __restrict__ h0img, const unsigned short* __restrict__ mlimg,
    const unsigned short* __restrict__ Wimg, Bias7 bz, float* __restrict__ out, int E){
  __shared__ unsigned short HA[128][128];
  __shared__ unsigned short HB[128][128];
  __shared__ unsigned short W0[128][128];
  __shared__ unsigned short W1[128][128];
  int tid = threadIdx.x;
  int row0 = blockIdx.x * 128;
  #pragma unroll
  for (int it = 0; it < 8; ++it){
    int lin = tid + it*256;
    ((uint4*)HA)[lin] = ((const uint4*)(h0img + (size_t)row0*128))[lin];
    ((uint4*)W0)[lin] = ((const uint4*)(Wimg + 2*16384))[lin];
  }
  __syncthreads();
  int wid = tid >> 6, lane = tid & 63;
  int wr = (wid >> 1)*64, wc = (wid & 1)*64;
  int lrow = lane & 15, lk = (lane >> 4)*8;
  int drow0 = (lane >> 4)*4, dcol = lane & 15;
  f32x4 acc[4][4];
  unsigned int R[4][4][2];
  float bc[4];

  auto stageW = [&](unsigned short (*dst)[128], int tile){
    #pragma unroll
    for (int it = 0; it < 8; ++it){
      int lin = tid + it*256;
      ((uint4*)dst)[lin] = ((const uint4*)(Wimg + (size_t)tile*16384))[lin];
    }
  };
  auto getb = [&](const float* b){
    #pragma unroll
    for (int n = 0; n < 4; ++n) bc[n] = b[wc + n*16 + dcol];
  };
  auto wstate = [&](unsigned short (*dst)[128], int m, int n, int q, float v){
    int r = wr + m*16 + drow0 + q, c = wc + n*16 + dcol;
    dst[r][c ^ ((r & 7) << 3)] = f2bf(v);
  };
  auto rstate = [&](const unsigned short (*src)[128], int m, int n, int q)->float{
    int r = wr + m*16 + drow0 + q, c = wc + n*16 + dcol;
    return bf2f(src[r][c ^ ((r & 7) << 3)]);
  };

  // s1: h1 = sw(h0 @ r1W1 + b) -> HB
  mfma_kloop(HA, W0, wr, wc, lrow, lk, acc);
  getb(bz.p[0]);
  stageW(W1, 3);
  #pragma unroll
  for (int m = 0; m < 4; ++m)
    #pragma unroll
    for (int n = 0; n < 4; ++n)
      #pragma unroll
      for (int q = 0; q < 4; ++q)
        wstate(HB, m, n, q, swishf(acc[m][n][q] + bc[n]));
  __syncthreads();

  // s2: h2 = h0 + sw(h1 @ r1W2 + b) -> HB ; ml -> HA
  mfma_kloop(HB, W1, wr, wc, lrow, lk, acc);
  getb(bz.p[1]);
  __syncthreads();                       // BAR1: done reading HB
  float h0v[4][4][4];
  #pragma unroll
  for (int m = 0; m < 4; ++m)
    #pragma unroll
    for (int n = 0; n < 4; ++n)
      #pragma unroll
      for (int q = 0; q < 4; ++q)
        h0v[m][n][q] = rstate(HA, m, n, q);
  __syncthreads();                       // BAR2: done reading HA (h0)
  stageW(W0, 4);
  #pragma unroll
  for (int it = 0; it < 8; ++it){
    int lin = tid + it*256;
    ((uint4*)HA)[lin] = ((const uint4*)(mlimg + (size_t)row0*128))[lin];
  }
  #pragma unroll
  for (int m = 0; m < 4; ++m)
    #pragma unroll
    for (int n = 0; n < 4; ++n)
      #pragma unroll
      for (int q = 0; q < 4; ++q)
        wstate(HB, m, n, q, h0v[m][n][q] + swishf(acc[m][n][q] + bc[n]));
  __syncthreads();

  // s3: h3 = sw(h2 @ Wbs + b) + ml -> HB ; R = h3
  mfma_kloop(HB, W0, wr, wc, lrow, lk, acc);
  getb(bz.p[2]);
  __syncthreads();                       // BAR1: done reading HB
  stageW(W1, 5);
  #pragma unroll
  for (int m = 0; m < 4; ++m)
    #pragma unroll
    for (int n = 0; n < 4; ++n){
      float v[4];
      #pragma unroll
      for (int q = 0; q < 4; ++q){
        v[q] = swishf(acc[m][n][q] + bc[n]) + rstate(HA, m, n, q);
        wstate(HB, m, n, q, v[q]);
      }
      R[m][n][0] = pack2bf(v[0], v[1]);
      R[m][n][1] = pack2bf(v[2], v[3]);
    }
  __syncthreads();

  // s4: h4 = sw(h3 @ r3W1 + b) -> HA
  mfma_kloop(HB, W1, wr, wc, lrow, lk, acc);
  getb(bz.p[3]);
  stageW(W0, 6);
  #pragma unroll
  for (int m = 0; m < 4; ++m)
    #pragma unroll
    for (int n = 0; n < 4; ++n)
      #pragma unroll
      for (int q = 0; q < 4; ++q)
        wstate(HA, m, n, q, swishf(acc[m][n][q] + bc[n]));
  __syncthreads();

  // s5: h5 = h3 + sw(h4 @ r3W2 + b) -> HB ; R = h5
  mfma_kloop(HA, W0, wr, wc, lrow, lk, acc);
  getb(bz.p[4]);
  stageW(W1, 7);
  #pragma unroll
  for (int m = 0; m < 4; ++m)
    #pragma unroll
    for (int n = 0; n < 4; ++n){
      float v[4];
      #pragma unroll
      for (int q = 0; q < 4; ++q){
        unsigned int u = R[m][n][q >> 1];
        float rv = (q & 1) ? bfhi(u) : bflo(u);
        v[q] = rv + swishf(acc[m][n][q] + bc[n]);
        wstate(HB, m, n, q, v[q]);
      }
      R[m][n][0] = pack2bf(v[0], v[1]);
      R[m][n][1] = pack2bf(v[2], v[3]);
    }
  __syncthreads();

  // s6: h6 = sw(h5 @ r4W1 + b) -> HA
  mfma_kloop(HB, W1, wr, wc, lrow, lk, acc);
  getb(bz.p[5]);
  stageW(W0, 8);
  #pragma unroll
  for (int m = 0; m < 4; ++m)
    #pragma unroll
    for (int n = 0; n < 4; ++n)
      #pragma unroll
      for (int q = 0; q < 4; ++q)
        wstate(HA, m, n, q, swishf(acc[m][n][q] + bc[n]));
  __syncthreads();

  // s7: out = h5 + sw(h6 @ r4W2 + b)  (f32 global)
  mfma_kloop(HA, W0, wr, wc, lrow, lk, acc);
  getb(bz.p[6]);
  #pragma unroll
  for (int m = 0; m < 4; ++m)
    #pragma unroll
    for (int n = 0; n < 4; ++n){
      int col = wc + n*16 + dcol;
      #pragma unroll
      for (int q = 0; q < 4; ++q){
        int grow = row0 + wr + m*16 + drow0 + q;
        if (grow < E){
          unsigned int u = R[m][n][q >> 1];
          float rv = (q & 1) ? bfhi(u) : bflo(u);
          out[(size_t)grow*128 + col] = rv + swishf(acc[m][n][q] + bc[n]);
        }
      }
    }
}

// ---------------- host ----------------
extern "C" void kernel_launch(void* const* d_in, const int* in_sizes, int n_in,
                              void* d_out, int out_size, void* d_ws, size_t ws_size,
                              hipStream_t stream){
  const float* m_l_1 = (const float*)d_in[0];
  const float* e_rbf = (const float*)d_in[1];
  const float* a_sbf = (const float*)d_in[2];
  const int* id_kj   = (const int*)d_in[3];
  const int* id_ji   = (const int*)d_in[4];
  const float* W_rbf = (const float*)d_in[5];
  const float* W_sbf = (const float*)d_in[6];
  const float* W_ji  = (const float*)d_in[7];
  const float* b_ji  = (const float*)d_in[8];
  const float* W_kj  = (const float*)d_in[9];
  const float* b_kj  = (const float*)d_in[10];
  const float* bilin = (const float*)d_in[11];
  const float* W_bs  = (const float*)d_in[12];
  const float* b_bs  = (const float*)d_in[13];
  const float* r1_W1 = (const float*)d_in[14]; const float* r1_b1 = (const float*)d_in[15];
  const float* r1_W2 = (const float*)d_in[16]; const float* r1_b2 = (const float*)d_in[17];
  const float* r3_W1 = (const float*)d_in[18]; const float* r3_b1 = (const float*)d_in[19];
  const float* r3_W2 = (const float*)d_in[20]; const float* r3_b2 = (const float*)d_in[21];
  const float* r4_W1 = (const float*)d_in[22]; const float* r4_b1 = (const float*)d_in[23];
  const float* r4_W2 = (const float*)d_in[24]; const float* r4_b2 = (const float*)d_in[25];

  const int E = in_sizes[0] / F;
  const int T = in_sizes[3];
  const int nTiles = (E + 127) / 128;
  const int Epad = nTiles * 128;

  char* ws = (char*)d_ws;
  size_t off = 0;
  auto alloc = [&](size_t b)->char*{
    char* p = ws + off;
    off = (off + b + 255) & ~(size_t)255;
    return p;
  };
  unsigned short* Y    = (unsigned short*)alloc((size_t)Epad*1024*2);
  unsigned short* mji  = (unsigned short*)alloc((size_t)Epad*F*2);
  unsigned short* mkj  = (unsigned short*)alloc((size_t)Epad*F*2);
  unsigned short* h0   = (unsigned short*)alloc((size_t)Epad*F*2);
  unsigned short* mlbf = (unsigned short*)alloc((size_t)Epad*F*2);
  uint4* apg  = (uint4*)alloc((size_t)T*16);
  int* pkj    = (int*)alloc((size_t)T*4);
  int* ppos   = (int*)alloc((size_t)T*4);
  int* counts = (int*)alloc((size_t)E*4);
  int* offs   = (int*)alloc((size_t)(E+1)*4);
  int* cursor = (int*)alloc((size_t)E*4);
  unsigned short* Wbt = (unsigned short*)alloc((size_t)9*16384*2);
  unsigned short* WtB = (unsigned short*)alloc((size_t)8*16384*2);
  if (off > ws_size) return;

  // CSR build
  hipMemsetAsync(counts, 0, (size_t)E*4, stream);
  hist_kernel<<<2048, 256, 0, stream>>>(id_ji, counts, T);
  scan_kernel<<<1, 1024, 0, stream>>>(counts, offs, cursor, E, T);
  fill_kernel<<<2048, 256, 0, stream>>>(id_ji, id_kj, cursor, pkj, ppos, T);

  // weight preps
  Ptrs9 p9;
  p9.p[0] = W_ji;  p9.p[1] = W_kj;  p9.p[2] = r1_W1; p9.p[3] = r1_W2; p9.p[4] = W_bs;
  p9.p[5] = r3_W1; p9.p[6] = r3_W2; p9.p[7] = r4_W1; p9.p[8] = r4_W2;
  prep_w_kernel<<<dim3(64, 9), 256, 0, stream>>>(p9, Wbt);
  prep_bilin_kernel<<<512, 256, 0, stream>>>(bilin, WtB);
  a_pre_kernel<<<(T + 255)/256, 256, 0, stream>>>(a_sbf, W_sbf, ppos, apg, T);

  head_kernel<<<nTiles, 256, 0, stream>>>(m_l_1, Wbt + 0*16384, Wbt + 1*16384,
                                          b_ji, b_kj, e_rbf, W_rbf,
                                          mji, mkj, mlbf, E);
  ygemm_kernel<<<dim3(nTiles, 8), 256, 0, stream>>>(mkj, WtB, Y);
  stage2_kernel<<<(E + 3)/4, 256, 0, stream>>>(offs, pkj, apg, Y, mji, h0, E);

  Bias7 bz;
  bz.p[0] = r1_b1; bz.p[1] = r1_b2; bz.p[2] = b_bs;
  bz.p[3] = r3_b1; bz.p[4] = r3_b2; bz.p[5] = r4_b1; bz.p[6] = r4_b2;
  chain_kernel<<<nTiles, 256, 0, stream>>>(h0, mlbf, Wbt, bz, (float*)d_out, E);
}

// Round 4
// 1313.196 us; speedup vs baseline: 1.3956x; 1.0399x over previous
//
#include <hip/hip_runtime.h>
#include <hip/hip_bf16.h>

#define F 128
#define NRAD 6
#define NSPH 42

typedef __attribute__((ext_vector_type(8))) short bf16x8;
typedef __attribute__((ext_vector_type(4))) float f32x4;

__device__ __forceinline__ float bflo(unsigned int v){ return __uint_as_float(v << 16); }
__device__ __forceinline__ float bfhi(unsigned int v){ return __uint_as_float(v & 0xFFFF0000u); }
__device__ __forceinline__ unsigned short f2bf(float f){
  unsigned int u = __float_as_uint(f);
  return (unsigned short)((u + 0x7FFFu + ((u >> 16) & 1u)) >> 16);
}
__device__ __forceinline__ float bf2f(unsigned short u){ return __uint_as_float(((unsigned int)u) << 16); }
__device__ __forceinline__ unsigned int pack2bf(float a, float b){
  return (unsigned int)f2bf(a) | ((unsigned int)f2bf(b) << 16);
}
__device__ __forceinline__ float swishf(float x){ return x / (1.f + __expf(-x)); }

// ---------------- CSR build ----------------
__global__ void hist_kernel(const int* __restrict__ id_ji, int* __restrict__ counts, int T){
  for (int i = blockIdx.x*blockDim.x + threadIdx.x; i < T; i += gridDim.x*blockDim.x)
    atomicAdd(&counts[id_ji[i]], 1);
}

__global__ __launch_bounds__(1024) void scan_kernel(const int* __restrict__ counts,
    int* __restrict__ offs, int* __restrict__ cursor, int E, int T){
  __shared__ int wtot[16];
  int tid = threadIdx.x;
  int chunk = (E + 1023) / 1024;
  int b = tid*chunk, e2 = min(E, b + chunk);
  int s = 0;
  for (int i = b; i < e2; ++i) s += counts[i];
  int lane = tid & 63, w = tid >> 6;
  int v = s;
  #pragma unroll
  for (int d = 1; d < 64; d <<= 1){ int t = __shfl_up(v, d); if (lane >= d) v += t; }
  if (lane == 63) wtot[w] = v;
  __syncthreads();
  if (w == 0){
    int x = (lane < 16) ? wtot[lane] : 0;
    #pragma unroll
    for (int d = 1; d < 16; d <<= 1){ int t = __shfl_up(x, d); if (lane >= d) x += t; }
    if (lane < 16) wtot[lane] = x;
  }
  __syncthreads();
  int base = (w ? wtot[w-1] : 0) + (v - s);
  for (int i = b; i < e2; ++i){ offs[i] = base; cursor[i] = base; base += counts[i]; }
  if (tid == 0) offs[E] = T;
}

// fill: pkj[pos] = id_kj[i]; ppos[i] = pos (inverse perm for a_pre scatter)
__global__ void fill_kernel(const int* __restrict__ id_ji, const int* __restrict__ id_kj,
                            int* __restrict__ cursor, int* __restrict__ pkj,
                            int* __restrict__ ppos, int T){
  for (int i = blockIdx.x*blockDim.x + threadIdx.x; i < T; i += gridDim.x*blockDim.x){
    int pos = atomicAdd(&cursor[id_ji[i]], 1);
    pkj[pos] = id_kj[i];
    ppos[i] = pos;
  }
}

// ---------------- weight prep (pre-swizzled LDS-image layouts) ----------------
struct Ptrs9 { const float* p[9]; };

// Bt[n][k] = W[k][n], stored as swizzled image: dst[n*128 + (k ^ ((n&7)<<3))]
__global__ void prep_w_kernel(Ptrs9 ps, unsigned short* __restrict__ dst){
  int i = blockIdx.y;
  const float* src = ps.p[i];
  int idx = blockIdx.x*256 + threadIdx.x;     // 0..16383
  int n = idx >> 7, k = idx & 127;
  dst[i*16384 + n*128 + (k ^ ((n & 7) << 3))] = f2bf(src[k*128 + n]);
}

// WtB image: row n = j*128+i (tile j, within-tile row i), col l; value bilin[i][j][l]
__global__ void prep_bilin_kernel(const float* __restrict__ bilin, unsigned short* __restrict__ dst){
  int t = blockIdx.x*256 + threadIdx.x;       // 0..131071
  int n = t >> 7, l = t & 127;
  int i = n & 127, j = n >> 7;
  int r = n & 127;
  dst[(size_t)n*128 + (l ^ ((r & 7) << 3))] = f2bf(bilin[(size_t)i*1024 + j*128 + l]);
}

// a8 = a_sbf @ W_sbf, scattered directly into perm order via ppos
__global__ __launch_bounds__(256) void a_pre_kernel(const float* __restrict__ a_sbf,
    const float* __restrict__ W_sbf, const int* __restrict__ ppos,
    uint4* __restrict__ apg, int T){
  __shared__ float tile[256*45];
  __shared__ float wsh[NSPH*8];
  int tid = threadIdx.x;
  int w0 = blockIdx.x*256;
  for (int i = tid; i < NSPH*8; i += 256) wsh[i] = W_sbf[i];
  int total = 256*NSPH;
  size_t base = (size_t)w0 * NSPH;
  for (int k = tid; k < total; k += 256){
    int r = k / NSPH, c = k - r*NSPH;
    float v = 0.f;
    if (w0 + r < T) v = a_sbf[base + k];
    tile[r*45 + c] = v;
  }
  __syncthreads();
  int wI = w0 + tid;
  if (wI >= T) return;
  float out[8] = {0,0,0,0,0,0,0,0};
  for (int s = 0; s < NSPH; ++s){
    float av = tile[tid*45 + s];
    #pragma unroll
    for (int j = 0; j < 8; ++j) out[j] += av * wsh[s*8 + j];
  }
  uint4 ov;
  ov.x = pack2bf(out[0], out[1]);
  ov.y = pack2bf(out[2], out[3]);
  ov.z = pack2bf(out[4], out[5]);
  ov.w = pack2bf(out[6], out[7]);
  apg[ppos[wI]] = ov;
}

// ---------------- shared MFMA helper ----------------
template<int MR, int NR>
__device__ __forceinline__ void mfma_kloop(
    const unsigned short (*As)[128], const unsigned short (*Ws)[128],
    int wr, int wc, int lrow, int lk, f32x4 acc[MR][NR]){
  #pragma unroll
  for (int m = 0; m < MR; ++m)
    #pragma unroll
    for (int n = 0; n < NR; ++n)
      acc[m][n] = (f32x4){0.f,0.f,0.f,0.f};
  #pragma unroll
  for (int k = 0; k < 4; ++k){
    bf16x8 af[MR], bf[NR];
    #pragma unroll
    for (int m = 0; m < MR; ++m){
      int r = wr + m*16 + lrow;
      int c = (k*32 + lk) ^ ((r & 7) << 3);
      af[m] = *(const bf16x8*)(&As[r][c]);
    }
    #pragma unroll
    for (int n = 0; n < NR; ++n){
      int r = wc + n*16 + lrow;
      int c = (k*32 + lk) ^ ((r & 7) << 3);
      bf[n] = *(const bf16x8*)(&Ws[r][c]);
    }
    #pragma unroll
    for (int m = 0; m < MR; ++m)
      #pragma unroll
      for (int n = 0; n < NR; ++n)
        acc[m][n] = __builtin_amdgcn_mfma_f32_16x16x32_bf16(af[m], bf[n], acc[m][n], 0, 0, 0);
  }
}

// ---------------- head: m_ji, m_kj (gated), mlbf in one pass (512 thr) ----------------
__global__ __launch_bounds__(512) void head_kernel(
    const float* __restrict__ A, const unsigned short* __restrict__ Wji,
    const unsigned short* __restrict__ Wkj,
    const float* __restrict__ b_ji, const float* __restrict__ b_kj,
    const float* __restrict__ e_rbf, const float* __restrict__ W_rbf,
    unsigned short* __restrict__ m_ji, unsigned short* __restrict__ m_kj,
    unsigned short* __restrict__ mlbf, int E){
  __shared__ unsigned short Hs[128][128];
  __shared__ unsigned short W1s[128][128];
  __shared__ unsigned short W2s[128][128];
  int tid = threadIdx.x;
  int row0 = blockIdx.x * 128;
  #pragma unroll
  for (int it = 0; it < 8; ++it){
    int lin = tid + it*512;
    int r = lin >> 5;
    int c = (lin & 31) * 4;
    float4 v = make_float4(0.f,0.f,0.f,0.f);
    bool ok = (row0 + r < E);
    if (ok) v = *(const float4*)(A + (size_t)(row0 + r)*128 + c);
    uint2 o; o.x = pack2bf(v.x, v.y); o.y = pack2bf(v.z, v.w);
    int cs = c ^ ((r & 7) << 3);
    *(uint2*)(&Hs[r][cs]) = o;
    if (ok) *(uint2*)(mlbf + (size_t)(row0 + r)*128 + cs) = o;
  }
  #pragma unroll
  for (int it = 0; it < 4; ++it){
    int lin = tid + it*512;
    ((uint4*)W1s)[lin] = ((const uint4*)Wji)[lin];
    ((uint4*)W2s)[lin] = ((const uint4*)Wkj)[lin];
  }
  __syncthreads();
  int wid = tid >> 6, lane = tid & 63;
  int wr = (wid >> 2)*64, wc = (wid & 3)*32;
  int lrow = lane & 15, lk = (lane >> 4)*8;
  f32x4 acc1[4][2], acc2[4][2];
  #pragma unroll
  for (int m = 0; m < 4; ++m)
    #pragma unroll
    for (int n = 0; n < 2; ++n){ acc1[m][n] = (f32x4){0,0,0,0}; acc2[m][n] = (f32x4){0,0,0,0}; }
  #pragma unroll
  for (int k = 0; k < 4; ++k){
    bf16x8 af[4], b1[2], b2[2];
    #pragma unroll
    for (int m = 0; m < 4; ++m){
      int r = wr + m*16 + lrow;
      int c = (k*32 + lk) ^ ((r & 7) << 3);
      af[m] = *(const bf16x8*)(&Hs[r][c]);
    }
    #pragma unroll
    for (int n = 0; n < 2; ++n){
      int r = wc + n*16 + lrow;
      int c = (k*32 + lk) ^ ((r & 7) << 3);
      b1[n] = *(const bf16x8*)(&W1s[r][c]);
      b2[n] = *(const bf16x8*)(&W2s[r][c]);
    }
    #pragma unroll
    for (int m = 0; m < 4; ++m)
      #pragma unroll
      for (int n = 0; n < 2; ++n){
        acc1[m][n] = __builtin_amdgcn_mfma_f32_16x16x32_bf16(af[m], b1[n], acc1[m][n], 0, 0, 0);
        acc2[m][n] = __builtin_amdgcn_mfma_f32_16x16x32_bf16(af[m], b2[n], acc2[m][n], 0, 0, 0);
      }
  }
  __syncthreads();
  int drow0 = (lane >> 4)*4, dcol = lane & 15;
  // ---- m_ji = swish(acc1 + b_ji) ----
  #pragma unroll
  for (int m = 0; m < 4; ++m)
    #pragma unroll
    for (int n = 0; n < 2; ++n){
      int col = wc + n*16 + dcol;
      float bv = b_ji[col];
      #pragma unroll
      for (int q = 0; q < 4; ++q){
        int r = wr + m*16 + drow0 + q;
        Hs[r][col ^ ((r & 7) << 3)] = f2bf(swishf(acc1[m][n][q] + bv));
      }
    }
  __syncthreads();
  #pragma unroll
  for (int it = 0; it < 4; ++it){
    int lin = tid + it*512;
    int r = lin >> 4; int c = (lin & 15)*8;
    uint4 d = *(const uint4*)(&Hs[r][c ^ ((r & 7) << 3)]);
    if (row0 + r < E) *(uint4*)(m_ji + (size_t)(row0 + r)*128 + c) = d;
  }
  __syncthreads();
  // ---- m_kj = swish(acc2 + b_kj) * (e_rbf @ W_rbf), stored as swizzled image ----
  float wrb[2][6];
  #pragma unroll
  for (int n = 0; n < 2; ++n){
    int col = wc + n*16 + dcol;
    #pragma unroll
    for (int rr = 0; rr < 6; ++rr) wrb[n][rr] = W_rbf[rr*128 + col];
  }
  #pragma unroll
  for (int m = 0; m < 4; ++m){
    #pragma unroll
    for (int q = 0; q < 4; ++q){
      int grow = row0 + wr + m*16 + drow0 + q;
      int er = (grow < E) ? grow : 0;
      float e0 = e_rbf[er*6+0], e1 = e_rbf[er*6+1], e2 = e_rbf[er*6+2];
      float e3 = e_rbf[er*6+3], e4 = e_rbf[er*6+4], e5 = e_rbf[er*6+5];
      int rloc = wr + m*16 + drow0 + q;
      #pragma unroll
      for (int n = 0; n < 2; ++n){
        int col = wc + n*16 + dcol;
        float g = e0*wrb[n][0] + e1*wrb[n][1] + e2*wrb[n][2]
                + e3*wrb[n][3] + e4*wrb[n][4] + e5*wrb[n][5];
        float v = swishf(acc2[m][n][q] + b_kj[col]) * g;
        Hs[rloc][col ^ ((rloc & 7) << 3)] = f2bf(v);
      }
    }
  }
  __syncthreads();
  #pragma unroll
  for (int it = 0; it < 4; ++it){
    int lin = tid + it*512;
    int r = lin >> 4;
    if (row0 + r < E)
      ((uint4*)(m_kj + (size_t)row0*128))[lin] = ((const uint4*)Hs)[lin];
  }
}

// ---------------- Y = m_kj @ bilin^T  [Epad,1024] ----------------
__global__ __launch_bounds__(256) void ygemm_kernel(
    const unsigned short* __restrict__ Aimg, const unsigned short* __restrict__ Bimg,
    unsigned short* __restrict__ Y){
  __shared__ unsigned short As[128][128];
  __shared__ unsigned short Bs[128][128];
  int tid = threadIdx.x;
  int row0 = blockIdx.x*128, bn = blockIdx.y;
  #pragma unroll
  for (int it = 0; it < 8; ++it){
    int lin = tid + it*256;
    ((uint4*)As)[lin] = ((const uint4*)(Aimg + (size_t)row0*128))[lin];
    ((uint4*)Bs)[lin] = ((const uint4*)(Bimg + (size_t)bn*16384))[lin];
  }
  __syncthreads();
  int wid = tid >> 6, lane = tid & 63;
  int wr = (wid >> 1)*64, wc = (wid & 1)*64;
  int lrow = lane & 15, lk = (lane >> 4)*8;
  f32x4 acc[4][4];
  mfma_kloop<4,4>(As, Bs, wr, wc, lrow, lk, acc);
  __syncthreads();
  int drow0 = (lane >> 4)*4, dcol = lane & 15;
  #pragma unroll
  for (int m = 0; m < 4; ++m)
    #pragma unroll
    for (int n = 0; n < 4; ++n)
      #pragma unroll
      for (int q = 0; q < 4; ++q){
        int r = wr + m*16 + drow0 + q;
        int col = wc + n*16 + dcol;
        As[r][col ^ ((r & 7) << 3)] = f2bf(acc[m][n][q]);
      }
  __syncthreads();
  #pragma unroll
  for (int it = 0; it < 8; ++it){
    int lin = tid + it*256;
    int r = lin >> 4; int c = (lin & 15)*8;
    uint4 d = *(const uint4*)(&As[r][c ^ ((r & 7) << 3)]);
    *(uint4*)(Y + (size_t)(row0 + r)*1024 + bn*128 + c) = d;
  }
}

// ---------------- stage 2: per-edge gather-reduce, j-half split ----------------
// PASS 0: cols j=0..3 (first half of Y rows), partial -> h0img (bf16, plain rows)
// PASS 1: cols j=4..7, add partial + m_ji, write swizzled h0 image in place
template<int PASS>
__global__ __launch_bounds__(256) void stage2_kernel(
    const int* __restrict__ offs, const int* __restrict__ pkj,
    const uint4* __restrict__ apg, const unsigned short* __restrict__ Y,
    const unsigned short* __restrict__ m_ji, unsigned short* __restrict__ h0img, int E){
  int e = blockIdx.x*4 + (threadIdx.x >> 6);
  if (e >= E) return;
  int lane = threadIdx.x & 63;
  int jsel = lane >> 4;
  int beg = offs[e], end = offs[e+1];
  float acc[8] = {0,0,0,0,0,0,0,0};
  int kj = 0; uint4 av = make_uint4(0,0,0,0);
  if (beg < end){ kj = pkj[beg]; av = apg[beg]; }
  for (int idx = beg; idx < end; ++idx){
    const uint4* yrow = (const uint4*)(Y + (size_t)kj*1024);
    uint4 y = (PASS == 0) ? yrow[lane] : yrow[64 + lane];
    int kjn = kj; uint4 avn = av;
    if (idx + 1 < end){ kjn = pkj[idx+1]; avn = apg[idx+1]; }
    unsigned int u;
    if (PASS == 0) u = (jsel & 2) ? av.y : av.x;
    else           u = (jsel & 2) ? av.w : av.z;
    float a = (jsel & 1) ? bfhi(u) : bflo(u);
    acc[0] += a*bflo(y.x); acc[1] += a*bfhi(y.x);
    acc[2] += a*bflo(y.y); acc[3] += a*bfhi(y.y);
    acc[4] += a*bflo(y.z); acc[5] += a*bfhi(y.z);
    acc[6] += a*bflo(y.w); acc[7] += a*bfhi(y.w);
    kj = kjn; av = avn;
  }
  #pragma unroll
  for (int q = 0; q < 8; ++q){
    acc[q] += __shfl_xor(acc[q], 16);
    acc[q] += __shfl_xor(acc[q], 32);
  }
  if (lane < 16){
    if (PASS == 0){
      uint4 o;
      o.x = pack2bf(acc[0], acc[1]); o.y = pack2bf(acc[2], acc[3]);
      o.z = pack2bf(acc[4], acc[5]); o.w = pack2bf(acc[6], acc[7]);
      ((uint4*)(h0img + (size_t)e*128))[lane] = o;           // plain partial
    } else {
      uint4 xp = ((const uint4*)(h0img + (size_t)e*128))[lane];
      acc[0] += bflo(xp.x); acc[1] += bfhi(xp.x);
      acc[2] += bflo(xp.y); acc[3] += bfhi(xp.y);
      acc[4] += bflo(xp.z); acc[5] += bfhi(xp.z);
      acc[6] += bflo(xp.w); acc[7] += bfhi(xp.w);
      uint4 mj = ((const uint4*)(m_ji + (size_t)e*128))[lane];
      acc[0] += bflo(mj.x); acc[1] += bfhi(mj.x);
      acc[2] += bflo(mj.y); acc[3] += bfhi(mj.y);
      acc[4] += bflo(mj.z); acc[5] += bfhi(mj.z);
      acc[6] += bflo(mj.w); acc[7] += bfhi(mj.w);
      uint4 o;
      o.x = pack2bf(acc[0], acc[1]); o.y = pack2bf(acc[2], acc[3]);
      o.z = pack2bf(acc[4], acc[5]); o.w = pack2bf(acc[6], acc[7]);
      ((uint4*)(h0img + (size_t)e*128))[lane ^ (e & 7)] = o; // swizzled image
    }
  }
}

// ---------------- fused residual chain: 7 GEMMs, state in LDS (512 thr) ----------------
struct Bias7 { const float* p[7]; };

__global__ __launch_bounds__(512) void chain_kernel(
    const unsigned short* __restrict__ h0img, const unsigned short* __restrict__ mlimg,
    const unsigned short* __restrict__ Wimg, Bias7 bz, float* __restrict__ out, int E){
  __shared__ unsigned short HA[128][128];
  __shared__ unsigned short HB[128][128];
  __shared__ unsigned short W0[128][128];
  __shared__ unsigned short W1[128][128];
  int tid = threadIdx.x;
  int row0 = blockIdx.x * 128;
  #pragma unroll
  for (int it = 0; it < 4; ++it){
    int lin = tid + it*512;
    ((uint4*)HA)[lin] = ((const uint4*)(h0img + (size_t)row0*128))[lin];
    ((uint4*)W0)[lin] = ((const uint4*)(Wimg + 2*16384))[lin];
  }
  __syncthreads();
  int wid = tid >> 6, lane = tid & 63;
  int wr = (wid >> 2)*64, wc = (wid & 3)*32;
  int lrow = lane & 15, lk = (lane >> 4)*8;
  int drow0 = (lane >> 4)*4, dcol = lane & 15;
  f32x4 acc[4][2];
  unsigned int R[4][2][2];
  float bc[2];

  auto stageW = [&](unsigned short (*dst)[128], int tile){
    #pragma unroll
    for (int it = 0; it < 4; ++it){
      int lin = tid + it*512;
      ((uint4*)dst)[lin] = ((const uint4*)(Wimg + (size_t)tile*16384))[lin];
    }
  };
  auto getb = [&](const float* b){
    #pragma unroll
    for (int n = 0; n < 2; ++n) bc[n] = b[wc + n*16 + dcol];
  };
  auto wstate = [&](unsigned short (*dst)[128], int m, int n, int q, float v){
    int r = wr + m*16 + drow0 + q, c = wc + n*16 + dcol;
    dst[r][c ^ ((r & 7) << 3)] = f2bf(v);
  };
  auto rstate = [&](const unsigned short (*src)[128], int m, int n, int q)->float{
    int r = wr + m*16 + drow0 + q, c = wc + n*16 + dcol;
    return bf2f(src[r][c ^ ((r & 7) << 3)]);
  };

  // s1: h1 = sw(h0 @ r1W1 + b) -> HB
  mfma_kloop<4,2>(HA, W0, wr, wc, lrow, lk, acc);
  getb(bz.p[0]);
  stageW(W1, 3);
  #pragma unroll
  for (int m = 0; m < 4; ++m)
    #pragma unroll
    for (int n = 0; n < 2; ++n)
      #pragma unroll
      for (int q = 0; q < 4; ++q)
        wstate(HB, m, n, q, swishf(acc[m][n][q] + bc[n]));
  __syncthreads();

  // s2: h2 = h0 + sw(h1 @ r1W2 + b) -> HB ; ml -> HA
  mfma_kloop<4,2>(HB, W1, wr, wc, lrow, lk, acc);
  getb(bz.p[1]);
  __syncthreads();                       // done reading HB
  float h0v[4][2][4];
  #pragma unroll
  for (int m = 0; m < 4; ++m)
    #pragma unroll
    for (int n = 0; n < 2; ++n)
      #pragma unroll
      for (int q = 0; q < 4; ++q)
        h0v[m][n][q] = rstate(HA, m, n, q);
  __syncthreads();                       // done reading HA (h0)
  stageW(W0, 4);
  #pragma unroll
  for (int it = 0; it < 4; ++it){
    int lin = tid + it*512;
    ((uint4*)HA)[lin] = ((const uint4*)(mlimg + (size_t)row0*128))[lin];
  }
  #pragma unroll
  for (int m = 0; m < 4; ++m)
    #pragma unroll
    for (int n = 0; n < 2; ++n)
      #pragma unroll
      for (int q = 0; q < 4; ++q)
        wstate(HB, m, n, q, h0v[m][n][q] + swishf(acc[m][n][q] + bc[n]));
  __syncthreads();

  // s3: h3 = sw(h2 @ Wbs + b) + ml -> HB ; R = h3
  mfma_kloop<4,2>(HB, W0, wr, wc, lrow, lk, acc);
  getb(bz.p[2]);
  __syncthreads();                       // done reading HB
  stageW(W1, 5);
  #pragma unroll
  for (int m = 0; m < 4; ++m)
    #pragma unroll
    for (int n = 0; n < 2; ++n){
      float v[4];
      #pragma unroll
      for (int q = 0; q < 4; ++q){
        v[q] = swishf(acc[m][n][q] + bc[n]) + rstate(HA, m, n, q);
        wstate(HB, m, n, q, v[q]);
      }
      R[m][n][0] = pack2bf(v[0], v[1]);
      R[m][n][1] = pack2bf(v[2], v[3]);
    }
  __syncthreads();

  // s4: h4 = sw(h3 @ r3W1 + b) -> HA
  mfma_kloop<4,2>(HB, W1, wr, wc, lrow, lk, acc);
  getb(bz.p[3]);
  stageW(W0, 6);
  #pragma unroll
  for (int m = 0; m < 4; ++m)
    #pragma unroll
    for (int n = 0; n < 2; ++n)
      #pragma unroll
      for (int q = 0; q < 4; ++q)
        wstate(HA, m, n, q, swishf(acc[m][n][q] + bc[n]));
  __syncthreads();

  // s5: h5 = h3 + sw(h4 @ r3W2 + b) -> HB ; R = h5
  mfma_kloop<4,2>(HA, W0, wr, wc, lrow, lk, acc);
  getb(bz.p[4]);
  stageW(W1, 7);
  #pragma unroll
  for (int m = 0; m < 4; ++m)
    #pragma unroll
    for (int n = 0; n < 2; ++n){
      float v[4];
      #pragma unroll
      for (int q = 0; q < 4; ++q){
        unsigned int u = R[m][n][q >> 1];
        float rv = (q & 1) ? bfhi(u) : bflo(u);
        v[q] = rv + swishf(acc[m][n][q] + bc[n]);
        wstate(HB, m, n, q, v[q]);
      }
      R[m][n][0] = pack2bf(v[0], v[1]);
      R[m][n][1] = pack2bf(v[2], v[3]);
    }
  __syncthreads();

  // s6: h6 = sw(h5 @ r4W1 + b) -> HA
  mfma_kloop<4,2>(HB, W1, wr, wc, lrow, lk, acc);
  getb(bz.p[5]);
  stageW(W0, 8);
  #pragma unroll
  for (int m = 0; m < 4; ++m)
    #pragma unroll
    for (int n = 0; n < 2; ++n)
      #pragma unroll
      for (int q = 0; q < 4; ++q)
        wstate(HA, m, n, q, swishf(acc[m][n][q] + bc[n]));
  __syncthreads();

  // s7: out = h5 + sw(h6 @ r4W2 + b)  (f32 global)
  mfma_kloop<4,2>(HA, W0, wr, wc, lrow, lk, acc);
  getb(bz.p[6]);
  #pragma unroll
  for (int m = 0; m < 4; ++m)
    #pragma unroll
    for (int n = 0; n < 2; ++n){
      int col = wc + n*16 + dcol;
      #pragma unroll
      for (int q = 0; q < 4; ++q){
        int grow = row0 + wr + m*16 + drow0 + q;
        if (grow < E){
          unsigned int u = R[m][n][q >> 1];
          float rv = (q & 1) ? bfhi(u) : bflo(u);
          out[(size_t)grow*128 + col] = rv + swishf(acc[m][n][q] + bc[n]);
        }
      }
    }
}

// ---------------- host ----------------
extern "C" void kernel_launch(void* const* d_in, const int* in_sizes, int n_in,
                              void* d_out, int out_size, void* d_ws, size_t ws_size,
                              hipStream_t stream){
  const float* m_l_1 = (const float*)d_in[0];
  const float* e_rbf = (const float*)d_in[1];
  const float* a_sbf = (const float*)d_in[2];
  const int* id_kj   = (const int*)d_in[3];
  const int* id_ji   = (const int*)d_in[4];
  const float* W_rbf = (const float*)d_in[5];
  const float* W_sbf = (const float*)d_in[6];
  const float* W_ji  = (const float*)d_in[7];
  const float* b_ji  = (const float*)d_in[8];
  const float* W_kj  = (const float*)d_in[9];
  const float* b_kj  = (const float*)d_in[10];
  const float* bilin = (const float*)d_in[11];
  const float* W_bs  = (const float*)d_in[12];
  const float* b_bs  = (const float*)d_in[13];
  const float* r1_W1 = (const float*)d_in[14]; const float* r1_b1 = (const float*)d_in[15];
  const float* r1_W2 = (const float*)d_in[16]; const float* r1_b2 = (const float*)d_in[17];
  const float* r3_W1 = (const float*)d_in[18]; const float* r3_b1 = (const float*)d_in[19];
  const float* r3_W2 = (const float*)d_in[20]; const float* r3_b2 = (const float*)d_in[21];
  const float* r4_W1 = (const float*)d_in[22]; const float* r4_b1 = (const float*)d_in[23];
  const float* r4_W2 = (const float*)d_in[24]; const float* r4_b2 = (const float*)d_in[25];

  const int E = in_sizes[0] / F;
  const int T = in_sizes[3];
  const int nTiles = (E + 127) / 128;
  const int Epad = nTiles * 128;

  char* ws = (char*)d_ws;
  size_t off = 0;
  auto alloc = [&](size_t b)->char*{
    char* p = ws + off;
    off = (off + b + 255) & ~(size_t)255;
    return p;
  };
  unsigned short* Y    = (unsigned short*)alloc((size_t)Epad*1024*2);
  unsigned short* mji  = (unsigned short*)alloc((size_t)Epad*F*2);
  unsigned short* mkj  = (unsigned short*)alloc((size_t)Epad*F*2);
  unsigned short* h0   = (unsigned short*)alloc((size_t)Epad*F*2);
  unsigned short* mlbf = (unsigned short*)alloc((size_t)Epad*F*2);
  uint4* apg  = (uint4*)alloc((size_t)T*16);
  int* pkj    = (int*)alloc((size_t)T*4);
  int* ppos   = (int*)alloc((size_t)T*4);
  int* counts = (int*)alloc((size_t)E*4);
  int* offs   = (int*)alloc((size_t)(E+1)*4);
  int* cursor = (int*)alloc((size_t)E*4);
  unsigned short* Wbt = (unsigned short*)alloc((size_t)9*16384*2);
  unsigned short* WtB = (unsigned short*)alloc((size_t)8*16384*2);
  if (off > ws_size) return;

  // CSR build
  hipMemsetAsync(counts, 0, (size_t)E*4, stream);
  hist_kernel<<<2048, 256, 0, stream>>>(id_ji, counts, T);
  scan_kernel<<<1, 1024, 0, stream>>>(counts, offs, cursor, E, T);
  fill_kernel<<<2048, 256, 0, stream>>>(id_ji, id_kj, cursor, pkj, ppos, T);

  // weight preps
  Ptrs9 p9;
  p9.p[0] = W_ji;  p9.p[1] = W_kj;  p9.p[2] = r1_W1; p9.p[3] = r1_W2; p9.p[4] = W_bs;
  p9.p[5] = r3_W1; p9.p[6] = r3_W2; p9.p[7] = r4_W1; p9.p[8] = r4_W2;
  prep_w_kernel<<<dim3(64, 9), 256, 0, stream>>>(p9, Wbt);
  prep_bilin_kernel<<<512, 256, 0, stream>>>(bilin, WtB);
  a_pre_kernel<<<(T + 255)/256, 256, 0, stream>>>(a_sbf, W_sbf, ppos, apg, T);

  head_kernel<<<nTiles, 512, 0, stream>>>(m_l_1, Wbt + 0*16384, Wbt + 1*16384,
                                          b_ji, b_kj, e_rbf, W_rbf,
                                          mji, mkj, mlbf, E);
  ygemm_kernel<<<dim3(nTiles, 8), 256, 0, stream>>>(mkj, WtB, Y);
  stage2_kernel<0><<<(E + 3)/4, 256, 0, stream>>>(offs, pkj, apg, Y, mji, h0, E);
  stage2_kernel<1><<<(E + 3)/4, 256, 0, stream>>>(offs, pkj, apg, Y, mji, h0, E);

  Bias7 bz;
  bz.p[0] = r1_b1; bz.p[1] = r1_b2; bz.p[2] = b_bs;
  bz.p[3] = r3_b1; bz.p[4] = r3_b2; bz.p[5] = r4_b1; bz.p[6] = r4_b2;
  chain_kernel<<<nTiles, 512, 0, stream>>>(h0, mlbf, Wbt, bz, (float*)d_out, E);
}

// Round 5
// 1104.092 us; speedup vs baseline: 1.6599x; 1.1894x over previous
//
#include <hip/hip_runtime.h>
#include <hip/hip_bf16.h>

#define F 128
#define NRAD 6
#define NSPH 42

typedef __attribute__((ext_vector_type(8))) short bf16x8;
typedef __attribute__((ext_vector_type(4))) float f32x4;

__device__ __forceinline__ float bflo(unsigned int v){ return __uint_as_float(v << 16); }
__device__ __forceinline__ float bfhi(unsigned int v){ return __uint_as_float(v & 0xFFFF0000u); }
__device__ __forceinline__ unsigned short f2bf(float f){
  unsigned int u = __float_as_uint(f);
  return (unsigned short)((u + 0x7FFFu + ((u >> 16) & 1u)) >> 16);
}
__device__ __forceinline__ float bf2f(unsigned short u){ return __uint_as_float(((unsigned int)u) << 16); }
__device__ __forceinline__ unsigned int pack2bf(float a, float b){
  return (unsigned int)f2bf(a) | ((unsigned int)f2bf(b) << 16);
}
__device__ __forceinline__ float swishf(float x){ return x / (1.f + __expf(-x)); }

// ---------------- CSR build ----------------
__global__ void hist_kernel(const int* __restrict__ id_ji, int* __restrict__ counts, int T){
  for (int i = blockIdx.x*blockDim.x + threadIdx.x; i < T; i += gridDim.x*blockDim.x)
    atomicAdd(&counts[id_ji[i]], 1);
}

// coalesced 2-level scan: blocksum -> scanpart -> scatter
__global__ __launch_bounds__(256) void blocksum_kernel(const int* __restrict__ counts,
    int* __restrict__ partial, int E){
  int base = blockIdx.x*1024;
  int tid = threadIdx.x;
  int s = 0;
  #pragma unroll
  for (int it = 0; it < 4; ++it){
    int i = base + tid + it*256;
    if (i < E) s += counts[i];
  }
  #pragma unroll
  for (int d = 1; d < 64; d <<= 1) s += __shfl_xor(s, d);
  __shared__ int ws[4];
  if ((tid & 63) == 0) ws[tid >> 6] = s;
  __syncthreads();
  if (tid == 0) partial[blockIdx.x] = ws[0] + ws[1] + ws[2] + ws[3];
}

__global__ __launch_bounds__(256) void scanpart_kernel(int* __restrict__ partial, int nb){
  __shared__ int sh[1024];
  int tid = threadIdx.x;
  for (int i = tid; i < nb; i += 256) sh[i] = partial[i];
  __syncthreads();
  if (tid == 0){
    int run = 0;
    for (int i = 0; i < nb; ++i){ int c = sh[i]; sh[i] = run; run += c; }
  }
  __syncthreads();
  for (int i = tid; i < nb; i += 256) partial[i] = sh[i];
}

__global__ __launch_bounds__(256) void scatter_kernel(const int* __restrict__ counts,
    const int* __restrict__ partial, int* __restrict__ offs, int* __restrict__ cursor,
    int E, int T){
  int base = blockIdx.x*1024;
  int tid = threadIdx.x;
  int i0 = base + tid*4;
  int4 c4 = make_int4(0,0,0,0);
  if (i0 + 3 < E) c4 = *(const int4*)(counts + i0);
  else {
    if (i0   < E) c4.x = counts[i0];
    if (i0+1 < E) c4.y = counts[i0+1];
    if (i0+2 < E) c4.z = counts[i0+2];
    if (i0+3 < E) c4.w = counts[i0+3];
  }
  int tsum = c4.x + c4.y + c4.z + c4.w;
  int lane = tid & 63, w = tid >> 6;
  int v = tsum;
  #pragma unroll
  for (int d = 1; d < 64; d <<= 1){ int t = __shfl_up(v, d); if (lane >= d) v += t; }
  __shared__ int ws[4];
  if (lane == 63) ws[w] = v;
  __syncthreads();
  int wb = 0;
  #pragma unroll
  for (int k = 0; k < 4; ++k) if (k < w) wb += ws[k];
  int run = partial[blockIdx.x] + wb + (v - tsum);
  int o0 = run;
  int o1 = o0 + c4.x;
  int o2 = o1 + c4.y;
  int o3 = o2 + c4.z;
  int4 o = make_int4(o0, o1, o2, o3);
  if (i0 + 3 < E){
    *(int4*)(offs + i0) = o;
    *(int4*)(cursor + i0) = o;
  } else {
    if (i0   < E){ offs[i0]   = o0; cursor[i0]   = o0; }
    if (i0+1 < E){ offs[i0+1] = o1; cursor[i0+1] = o1; }
    if (i0+2 < E){ offs[i0+2] = o2; cursor[i0+2] = o2; }
    if (i0+3 < E){ offs[i0+3] = o3; cursor[i0+3] = o3; }
  }
  if (blockIdx.x == 0 && tid == 0) offs[E] = T;
}

// fill: pkj[pos] = id_kj[i]; ppos[i] = pos (inverse perm for a_pre scatter)
__global__ void fill_kernel(const int* __restrict__ id_ji, const int* __restrict__ id_kj,
                            int* __restrict__ cursor, int* __restrict__ pkj,
                            int* __restrict__ ppos, int T){
  for (int i = blockIdx.x*blockDim.x + threadIdx.x; i < T; i += gridDim.x*blockDim.x){
    int pos = atomicAdd(&cursor[id_ji[i]], 1);
    pkj[pos] = id_kj[i];
    ppos[i] = pos;
  }
}

// ---------------- weight prep (pre-swizzled LDS-image layouts) ----------------
struct Ptrs9 { const float* p[9]; };

// Bt[n][k] = W[k][n], stored as swizzled image: dst[n*128 + (k ^ ((n&7)<<3))]
__global__ void prep_w_kernel(Ptrs9 ps, unsigned short* __restrict__ dst){
  int i = blockIdx.y;
  const float* src = ps.p[i];
  int idx = blockIdx.x*256 + threadIdx.x;     // 0..16383
  int n = idx >> 7, k = idx & 127;
  dst[i*16384 + n*128 + (k ^ ((n & 7) << 3))] = f2bf(src[k*128 + n]);
}

// WtB image: row n = j*128+i (tile j, within-tile row i), col l; value bilin[i][j][l]
__global__ void prep_bilin_kernel(const float* __restrict__ bilin, unsigned short* __restrict__ dst){
  int t = blockIdx.x*256 + threadIdx.x;       // 0..131071
  int n = t >> 7, l = t & 127;
  int i = n & 127, j = n >> 7;
  int r = n & 127;
  dst[(size_t)n*128 + (l ^ ((r & 7) << 3))] = f2bf(bilin[(size_t)i*1024 + j*128 + l]);
}

// a8 = a_sbf @ W_sbf, scattered directly into perm order via ppos
__global__ __launch_bounds__(256) void a_pre_kernel(const float* __restrict__ a_sbf,
    const float* __restrict__ W_sbf, const int* __restrict__ ppos,
    uint4* __restrict__ apg, int T){
  __shared__ float tile[256*45];
  __shared__ float wsh[NSPH*8];
  int tid = threadIdx.x;
  int w0 = blockIdx.x*256;
  for (int i = tid; i < NSPH*8; i += 256) wsh[i] = W_sbf[i];
  int total = 256*NSPH;
  size_t base = (size_t)w0 * NSPH;
  for (int k = tid; k < total; k += 256){
    int r = k / NSPH, c = k - r*NSPH;
    float v = 0.f;
    if (w0 + r < T) v = a_sbf[base + k];
    tile[r*45 + c] = v;
  }
  __syncthreads();
  int wI = w0 + tid;
  if (wI >= T) return;
  float out[8] = {0,0,0,0,0,0,0,0};
  for (int s = 0; s < NSPH; ++s){
    float av = tile[tid*45 + s];
    #pragma unroll
    for (int j = 0; j < 8; ++j) out[j] += av * wsh[s*8 + j];
  }
  uint4 ov;
  ov.x = pack2bf(out[0], out[1]);
  ov.y = pack2bf(out[2], out[3]);
  ov.z = pack2bf(out[4], out[5]);
  ov.w = pack2bf(out[6], out[7]);
  apg[ppos[wI]] = ov;
}

// ---------------- shared MFMA helper ----------------
template<int MR, int NR>
__device__ __forceinline__ void mfma_kloop(
    const unsigned short (*As)[128], const unsigned short (*Ws)[128],
    int wr, int wc, int lrow, int lk, f32x4 acc[MR][NR]){
  #pragma unroll
  for (int m = 0; m < MR; ++m)
    #pragma unroll
    for (int n = 0; n < NR; ++n)
      acc[m][n] = (f32x4){0.f,0.f,0.f,0.f};
  #pragma unroll
  for (int k = 0; k < 4; ++k){
    bf16x8 af[MR], bf[NR];
    #pragma unroll
    for (int m = 0; m < MR; ++m){
      int r = wr + m*16 + lrow;
      int c = (k*32 + lk) ^ ((r & 7) << 3);
      af[m] = *(const bf16x8*)(&As[r][c]);
    }
    #pragma unroll
    for (int n = 0; n < NR; ++n){
      int r = wc + n*16 + lrow;
      int c = (k*32 + lk) ^ ((r & 7) << 3);
      bf[n] = *(const bf16x8*)(&Ws[r][c]);
    }
    #pragma unroll
    for (int m = 0; m < MR; ++m)
      #pragma unroll
      for (int n = 0; n < NR; ++n)
        acc[m][n] = __builtin_amdgcn_mfma_f32_16x16x32_bf16(af[m], bf[n], acc[m][n], 0, 0, 0);
  }
}

// ---------------- head: m_ji, m_kj (gated), mlbf in one pass (512 thr) ----------------
__global__ __launch_bounds__(512) void head_kernel(
    const float* __restrict__ A, const unsigned short* __restrict__ Wji,
    const unsigned short* __restrict__ Wkj,
    const float* __restrict__ b_ji, const float* __restrict__ b_kj,
    const float* __restrict__ e_rbf, const float* __restrict__ W_rbf,
    unsigned short* __restrict__ m_ji, unsigned short* __restrict__ m_kj,
    unsigned short* __restrict__ mlbf, int E){
  __shared__ unsigned short Hs[128][128];
  __shared__ unsigned short W1s[128][128];
  __shared__ unsigned short W2s[128][128];
  int tid = threadIdx.x;
  int row0 = blockIdx.x * 128;
  #pragma unroll
  for (int it = 0; it < 8; ++it){
    int lin = tid + it*512;
    int r = lin >> 5;
    int c = (lin & 31) * 4;
    float4 v = make_float4(0.f,0.f,0.f,0.f);
    bool ok = (row0 + r < E);
    if (ok) v = *(const float4*)(A + (size_t)(row0 + r)*128 + c);
    uint2 o; o.x = pack2bf(v.x, v.y); o.y = pack2bf(v.z, v.w);
    int cs = c ^ ((r & 7) << 3);
    *(uint2*)(&Hs[r][cs]) = o;
    if (ok) *(uint2*)(mlbf + (size_t)(row0 + r)*128 + cs) = o;
  }
  #pragma unroll
  for (int it = 0; it < 4; ++it){
    int lin = tid + it*512;
    ((uint4*)W1s)[lin] = ((const uint4*)Wji)[lin];
    ((uint4*)W2s)[lin] = ((const uint4*)Wkj)[lin];
  }
  __syncthreads();
  int wid = tid >> 6, lane = tid & 63;
  int wr = (wid >> 2)*64, wc = (wid & 3)*32;
  int lrow = lane & 15, lk = (lane >> 4)*8;
  f32x4 acc1[4][2], acc2[4][2];
  #pragma unroll
  for (int m = 0; m < 4; ++m)
    #pragma unroll
    for (int n = 0; n < 2; ++n){ acc1[m][n] = (f32x4){0,0,0,0}; acc2[m][n] = (f32x4){0,0,0,0}; }
  #pragma unroll
  for (int k = 0; k < 4; ++k){
    bf16x8 af[4], b1[2], b2[2];
    #pragma unroll
    for (int m = 0; m < 4; ++m){
      int r = wr + m*16 + lrow;
      int c = (k*32 + lk) ^ ((r & 7) << 3);
      af[m] = *(const bf16x8*)(&Hs[r][c]);
    }
    #pragma unroll
    for (int n = 0; n < 2; ++n){
      int r = wc + n*16 + lrow;
      int c = (k*32 + lk) ^ ((r & 7) << 3);
      b1[n] = *(const bf16x8*)(&W1s[r][c]);
      b2[n] = *(const bf16x8*)(&W2s[r][c]);
    }
    #pragma unroll
    for (int m = 0; m < 4; ++m)
      #pragma unroll
      for (int n = 0; n < 2; ++n){
        acc1[m][n] = __builtin_amdgcn_mfma_f32_16x16x32_bf16(af[m], b1[n], acc1[m][n], 0, 0, 0);
        acc2[m][n] = __builtin_amdgcn_mfma_f32_16x16x32_bf16(af[m], b2[n], acc2[m][n], 0, 0, 0);
      }
  }
  __syncthreads();
  int drow0 = (lane >> 4)*4, dcol = lane & 15;
  // ---- m_ji = swish(acc1 + b_ji) ----
  #pragma unroll
  for (int m = 0; m < 4; ++m)
    #pragma unroll
    for (int n = 0; n < 2; ++n){
      int col = wc + n*16 + dcol;
      float bv = b_ji[col];
      #pragma unroll
      for (int q = 0; q < 4; ++q){
        int r = wr + m*16 + drow0 + q;
        Hs[r][col ^ ((r & 7) << 3)] = f2bf(swishf(acc1[m][n][q] + bv));
      }
    }
  __syncthreads();
  #pragma unroll
  for (int it = 0; it < 4; ++it){
    int lin = tid + it*512;
    int r = lin >> 4; int c = (lin & 15)*8;
    uint4 d = *(const uint4*)(&Hs[r][c ^ ((r & 7) << 3)]);
    if (row0 + r < E) *(uint4*)(m_ji + (size_t)(row0 + r)*128 + c) = d;
  }
  __syncthreads();
  // ---- m_kj = swish(acc2 + b_kj) * (e_rbf @ W_rbf), stored as swizzled image ----
  float wrb[2][6];
  #pragma unroll
  for (int n = 0; n < 2; ++n){
    int col = wc + n*16 + dcol;
    #pragma unroll
    for (int rr = 0; rr < 6; ++rr) wrb[n][rr] = W_rbf[rr*128 + col];
  }
  #pragma unroll
  for (int m = 0; m < 4; ++m){
    #pragma unroll
    for (int q = 0; q < 4; ++q){
      int grow = row0 + wr + m*16 + drow0 + q;
      int er = (grow < E) ? grow : 0;
      float e0 = e_rbf[er*6+0], e1 = e_rbf[er*6+1], e2 = e_rbf[er*6+2];
      float e3 = e_rbf[er*6+3], e4 = e_rbf[er*6+4], e5 = e_rbf[er*6+5];
      int rloc = wr + m*16 + drow0 + q;
      #pragma unroll
      for (int n = 0; n < 2; ++n){
        int col = wc + n*16 + dcol;
        float g = e0*wrb[n][0] + e1*wrb[n][1] + e2*wrb[n][2]
                + e3*wrb[n][3] + e4*wrb[n][4] + e5*wrb[n][5];
        float v = swishf(acc2[m][n][q] + b_kj[col]) * g;
        Hs[rloc][col ^ ((rloc & 7) << 3)] = f2bf(v);
      }
    }
  }
  __syncthreads();
  #pragma unroll
  for (int it = 0; it < 4; ++it){
    int lin = tid + it*512;
    int r = lin >> 4;
    if (row0 + r < E)
      ((uint4*)(m_kj + (size_t)row0*128))[lin] = ((const uint4*)Hs)[lin];
  }
}

// ---------------- Y = m_kj @ bilin^T  [Epad,1024] ----------------
__global__ __launch_bounds__(256) void ygemm_kernel(
    const unsigned short* __restrict__ Aimg, const unsigned short* __restrict__ Bimg,
    unsigned short* __restrict__ Y){
  __shared__ unsigned short As[128][128];
  __shared__ unsigned short Bs[128][128];
  int tid = threadIdx.x;
  int row0 = blockIdx.x*128, bn = blockIdx.y;
  #pragma unroll
  for (int it = 0; it < 8; ++it){
    int lin = tid + it*256;
    ((uint4*)As)[lin] = ((const uint4*)(Aimg + (size_t)row0*128))[lin];
    ((uint4*)Bs)[lin] = ((const uint4*)(Bimg + (size_t)bn*16384))[lin];
  }
  __syncthreads();
  int wid = tid >> 6, lane = tid & 63;
  int wr = (wid >> 1)*64, wc = (wid & 1)*64;
  int lrow = lane & 15, lk = (lane >> 4)*8;
  f32x4 acc[4][4];
  mfma_kloop<4,4>(As, Bs, wr, wc, lrow, lk, acc);
  __syncthreads();
  int drow0 = (lane >> 4)*4, dcol = lane & 15;
  #pragma unroll
  for (int m = 0; m < 4; ++m)
    #pragma unroll
    for (int n = 0; n < 4; ++n)
      #pragma unroll
      for (int q = 0; q < 4; ++q){
        int r = wr + m*16 + drow0 + q;
        int col = wc + n*16 + dcol;
        As[r][col ^ ((r & 7) << 3)] = f2bf(acc[m][n][q]);
      }
  __syncthreads();
  #pragma unroll
  for (int it = 0; it < 8; ++it){
    int lin = tid + it*256;
    int r = lin >> 4; int c = (lin & 15)*8;
    uint4 d = *(const uint4*)(&As[r][c ^ ((r & 7) << 3)]);
    *(uint4*)(Y + (size_t)(row0 + r)*1024 + bn*128 + c) = d;
  }
}

// ---------------- stage 2: per-edge gather-reduce, j-half split ----------------
// PASS 0: cols j=0..3 (first half of Y rows), partial -> h0img (bf16, plain rows)
// PASS 1: cols j=4..7, add partial + m_ji, write swizzled h0 image in place
template<int PASS>
__global__ __launch_bounds__(256) void stage2_kernel(
    const int* __restrict__ offs, const int* __restrict__ pkj,
    const uint4* __restrict__ apg, const unsigned short* __restrict__ Y,
    const unsigned short* __restrict__ m_ji, unsigned short* __restrict__ h0img, int E){
  int e = blockIdx.x*4 + (threadIdx.x >> 6);
  if (e >= E) return;
  int lane = threadIdx.x & 63;
  int jsel = lane >> 4;
  int beg = offs[e], end = offs[e+1];
  float acc[8] = {0,0,0,0,0,0,0,0};
  int kj = 0; uint4 av = make_uint4(0,0,0,0);
  if (beg < end){ kj = pkj[beg]; av = apg[beg]; }
  for (int idx = beg; idx < end; ++idx){
    const uint4* yrow = (const uint4*)(Y + (size_t)kj*1024);
    uint4 y = (PASS == 0) ? yrow[lane] : yrow[64 + lane];
    int kjn = kj; uint4 avn = av;
    if (idx + 1 < end){ kjn = pkj[idx+1]; avn = apg[idx+1]; }
    unsigned int u;
    if (PASS == 0) u = (jsel & 2) ? av.y : av.x;
    else           u = (jsel & 2) ? av.w : av.z;
    float a = (jsel & 1) ? bfhi(u) : bflo(u);
    acc[0] += a*bflo(y.x); acc[1] += a*bfhi(y.x);
    acc[2] += a*bflo(y.y); acc[3] += a*bfhi(y.y);
    acc[4] += a*bflo(y.z); acc[5] += a*bfhi(y.z);
    acc[6] += a*bflo(y.w); acc[7] += a*bfhi(y.w);
    kj = kjn; av = avn;
  }
  #pragma unroll
  for (int q = 0; q < 8; ++q){
    acc[q] += __shfl_xor(acc[q], 16);
    acc[q] += __shfl_xor(acc[q], 32);
  }
  if (lane < 16){
    if (PASS == 0){
      uint4 o;
      o.x = pack2bf(acc[0], acc[1]); o.y = pack2bf(acc[2], acc[3]);
      o.z = pack2bf(acc[4], acc[5]); o.w = pack2bf(acc[6], acc[7]);
      ((uint4*)(h0img + (size_t)e*128))[lane] = o;           // plain partial
    } else {
      uint4 xp = ((const uint4*)(h0img + (size_t)e*128))[lane];
      acc[0] += bflo(xp.x); acc[1] += bfhi(xp.x);
      acc[2] += bflo(xp.y); acc[3] += bfhi(xp.y);
      acc[4] += bflo(xp.z); acc[5] += bfhi(xp.z);
      acc[6] += bflo(xp.w); acc[7] += bfhi(xp.w);
      uint4 mj = ((const uint4*)(m_ji + (size_t)e*128))[lane];
      acc[0] += bflo(mj.x); acc[1] += bfhi(mj.x);
      acc[2] += bflo(mj.y); acc[3] += bfhi(mj.y);
      acc[4] += bflo(mj.z); acc[5] += bfhi(mj.z);
      acc[6] += bflo(mj.w); acc[7] += bfhi(mj.w);
      uint4 o;
      o.x = pack2bf(acc[0], acc[1]); o.y = pack2bf(acc[2], acc[3]);
      o.z = pack2bf(acc[4], acc[5]); o.w = pack2bf(acc[6], acc[7]);
      ((uint4*)(h0img + (size_t)e*128))[lane ^ (e & 7)] = o; // swizzled image
    }
  }
}

// ---------------- fused residual chain: 7 GEMMs, state in LDS (512 thr) ----------------
struct Bias7 { const float* p[7]; };

__global__ __launch_bounds__(512) void chain_kernel(
    const unsigned short* __restrict__ h0img, const unsigned short* __restrict__ mlimg,
    const unsigned short* __restrict__ Wimg, Bias7 bz, float* __restrict__ out, int E){
  __shared__ unsigned short HA[128][128];
  __shared__ unsigned short HB[128][128];
  __shared__ unsigned short W0[128][128];
  __shared__ unsigned short W1[128][128];
  int tid = threadIdx.x;
  int row0 = blockIdx.x * 128;
  #pragma unroll
  for (int it = 0; it < 4; ++it){
    int lin = tid + it*512;
    ((uint4*)HA)[lin] = ((const uint4*)(h0img + (size_t)row0*128))[lin];
    ((uint4*)W0)[lin] = ((const uint4*)(Wimg + 2*16384))[lin];
  }
  __syncthreads();
  int wid = tid >> 6, lane = tid & 63;
  int wr = (wid >> 2)*64, wc = (wid & 3)*32;
  int lrow = lane & 15, lk = (lane >> 4)*8;
  int drow0 = (lane >> 4)*4, dcol = lane & 15;
  f32x4 acc[4][2];
  unsigned int R[4][2][2];
  float bc[2];

  auto stageW = [&](unsigned short (*dst)[128], int tile){
    #pragma unroll
    for (int it = 0; it < 4; ++it){
      int lin = tid + it*512;
      ((uint4*)dst)[lin] = ((const uint4*)(Wimg + (size_t)tile*16384))[lin];
    }
  };
  auto getb = [&](const float* b){
    #pragma unroll
    for (int n = 0; n < 2; ++n) bc[n] = b[wc + n*16 + dcol];
  };
  auto wstate = [&](unsigned short (*dst)[128], int m, int n, int q, float v){
    int r = wr + m*16 + drow0 + q, c = wc + n*16 + dcol;
    dst[r][c ^ ((r & 7) << 3)] = f2bf(v);
  };
  auto rstate = [&](const unsigned short (*src)[128], int m, int n, int q)->float{
    int r = wr + m*16 + drow0 + q, c = wc + n*16 + dcol;
    return bf2f(src[r][c ^ ((r & 7) << 3)]);
  };

  // s1: h1 = sw(h0 @ r1W1 + b) -> HB
  mfma_kloop<4,2>(HA, W0, wr, wc, lrow, lk, acc);
  getb(bz.p[0]);
  stageW(W1, 3);
  #pragma unroll
  for (int m = 0; m < 4; ++m)
    #pragma unroll
    for (int n = 0; n < 2; ++n)
      #pragma unroll
      for (int q = 0; q < 4; ++q)
        wstate(HB, m, n, q, swishf(acc[m][n][q] + bc[n]));
  __syncthreads();

  // s2: h2 = h0 + sw(h1 @ r1W2 + b) -> HB ; ml -> HA
  mfma_kloop<4,2>(HB, W1, wr, wc, lrow, lk, acc);
  getb(bz.p[1]);
  __syncthreads();                       // done reading HB
  float h0v[4][2][4];
  #pragma unroll
  for (int m = 0; m < 4; ++m)
    #pragma unroll
    for (int n = 0; n < 2; ++n)
      #pragma unroll
      for (int q = 0; q < 4; ++q)
        h0v[m][n][q] = rstate(HA, m, n, q);
  __syncthreads();                       // done reading HA (h0)
  stageW(W0, 4);
  #pragma unroll
  for (int it = 0; it < 4; ++it){
    int lin = tid + it*512;
    ((uint4*)HA)[lin] = ((const uint4*)(mlimg + (size_t)row0*128))[lin];
  }
  #pragma unroll
  for (int m = 0; m < 4; ++m)
    #pragma unroll
    for (int n = 0; n < 2; ++n)
      #pragma unroll
      for (int q = 0; q < 4; ++q)
        wstate(HB, m, n, q, h0v[m][n][q] + swishf(acc[m][n][q] + bc[n]));
  __syncthreads();

  // s3: h3 = sw(h2 @ Wbs + b) + ml -> HB ; R = h3
  mfma_kloop<4,2>(HB, W0, wr, wc, lrow, lk, acc);
  getb(bz.p[2]);
  __syncthreads();                       // done reading HB
  stageW(W1, 5);
  #pragma unroll
  for (int m = 0; m < 4; ++m)
    #pragma unroll
    for (int n = 0; n < 2; ++n){
      float v[4];
      #pragma unroll
      for (int q = 0; q < 4; ++q){
        v[q] = swishf(acc[m][n][q] + bc[n]) + rstate(HA, m, n, q);
        wstate(HB, m, n, q, v[q]);
      }
      R[m][n][0] = pack2bf(v[0], v[1]);
      R[m][n][1] = pack2bf(v[2], v[3]);
    }
  __syncthreads();

  // s4: h4 = sw(h3 @ r3W1 + b) -> HA
  mfma_kloop<4,2>(HB, W1, wr, wc, lrow, lk, acc);
  getb(bz.p[3]);
  stageW(W0, 6);
  #pragma unroll
  for (int m = 0; m < 4; ++m)
    #pragma unroll
    for (int n = 0; n < 2; ++n)
      #pragma unroll
      for (int q = 0; q < 4; ++q)
        wstate(HA, m, n, q, swishf(acc[m][n][q] + bc[n]));
  __syncthreads();

  // s5: h5 = h3 + sw(h4 @ r3W2 + b) -> HB ; R = h5
  mfma_kloop<4,2>(HA, W0, wr, wc, lrow, lk, acc);
  getb(bz.p[4]);
  stageW(W1, 7);
  #pragma unroll
  for (int m = 0; m < 4; ++m)
    #pragma unroll
    for (int n = 0; n < 2; ++n){
      float v[4];
      #pragma unroll
      for (int q = 0; q < 4; ++q){
        unsigned int u = R[m][n][q >> 1];
        float rv = (q & 1) ? bfhi(u) : bflo(u);
        v[q] = rv + swishf(acc[m][n][q] + bc[n]);
        wstate(HB, m, n, q, v[q]);
      }
      R[m][n][0] = pack2bf(v[0], v[1]);
      R[m][n][1] = pack2bf(v[2], v[3]);
    }
  __syncthreads();

  // s6: h6 = sw(h5 @ r4W1 + b) -> HA
  mfma_kloop<4,2>(HB, W1, wr, wc, lrow, lk, acc);
  getb(bz.p[5]);
  stageW(W0, 8);
  #pragma unroll
  for (int m = 0; m < 4; ++m)
    #pragma unroll
    for (int n = 0; n < 2; ++n)
      #pragma unroll
      for (int q = 0; q < 4; ++q)
        wstate(HA, m, n, q, swishf(acc[m][n][q] + bc[n]));
  __syncthreads();

  // s7: out = h5 + sw(h6 @ r4W2 + b)  (f32 global)
  mfma_kloop<4,2>(HA, W0, wr, wc, lrow, lk, acc);
  getb(bz.p[6]);
  #pragma unroll
  for (int m = 0; m < 4; ++m)
    #pragma unroll
    for (int n = 0; n < 2; ++n){
      int col = wc + n*16 + dcol;
      #pragma unroll
      for (int q = 0; q < 4; ++q){
        int grow = row0 + wr + m*16 + drow0 + q;
        if (grow < E){
          unsigned int u = R[m][n][q >> 1];
          float rv = (q & 1) ? bfhi(u) : bflo(u);
          out[(size_t)grow*128 + col] = rv + swishf(acc[m][n][q] + bc[n]);
        }
      }
    }
}

// ---------------- host ----------------
extern "C" void kernel_launch(void* const* d_in, const int* in_sizes, int n_in,
                              void* d_out, int out_size, void* d_ws, size_t ws_size,
                              hipStream_t stream){
  const float* m_l_1 = (const float*)d_in[0];
  const float* e_rbf = (const float*)d_in[1];
  const float* a_sbf = (const float*)d_in[2];
  const int* id_kj   = (const int*)d_in[3];
  const int* id_ji   = (const int*)d_in[4];
  const float* W_rbf = (const float*)d_in[5];
  const float* W_sbf = (const float*)d_in[6];
  const float* W_ji  = (const float*)d_in[7];
  const float* b_ji  = (const float*)d_in[8];
  const float* W_kj  = (const float*)d_in[9];
  const float* b_kj  = (const float*)d_in[10];
  const float* bilin = (const float*)d_in[11];
  const float* W_bs  = (const float*)d_in[12];
  const float* b_bs  = (const float*)d_in[13];
  const float* r1_W1 = (const float*)d_in[14]; const float* r1_b1 = (const float*)d_in[15];
  const float* r1_W2 = (const float*)d_in[16]; const float* r1_b2 = (const float*)d_in[17];
  const float* r3_W1 = (const float*)d_in[18]; const float* r3_b1 = (const float*)d_in[19];
  const float* r3_W2 = (const float*)d_in[20]; const float* r3_b2 = (const float*)d_in[21];
  const float* r4_W1 = (const float*)d_in[22]; const float* r4_b1 = (const float*)d_in[23];
  const float* r4_W2 = (const float*)d_in[24]; const float* r4_b2 = (const float*)d_in[25];

  const int E = in_sizes[0] / F;
  const int T = in_sizes[3];
  const int nTiles = (E + 127) / 128;
  const int Epad = nTiles * 128;
  const int nSeg = (E + 1023) / 1024;

  char* ws = (char*)d_ws;
  size_t off = 0;
  auto alloc = [&](size_t b)->char*{
    char* p = ws + off;
    off = (off + b + 255) & ~(size_t)255;
    return p;
  };
  unsigned short* Y    = (unsigned short*)alloc((size_t)Epad*1024*2);
  unsigned short* mji  = (unsigned short*)alloc((size_t)Epad*F*2);
  unsigned short* mkj  = (unsigned short*)alloc((size_t)Epad*F*2);
  unsigned short* h0   = (unsigned short*)alloc((size_t)Epad*F*2);
  unsigned short* mlbf = (unsigned short*)alloc((size_t)Epad*F*2);
  uint4* apg  = (uint4*)alloc((size_t)T*16);
  int* pkj    = (int*)alloc((size_t)T*4);
  int* ppos   = (int*)alloc((size_t)T*4);
  int* counts = (int*)alloc((size_t)E*4);
  int* offs   = (int*)alloc((size_t)(E+1)*4);
  int* cursor = (int*)alloc((size_t)E*4);
  int* partial= (int*)alloc((size_t)(nSeg+1)*4);
  unsigned short* Wbt = (unsigned short*)alloc((size_t)9*16384*2);
  unsigned short* WtB = (unsigned short*)alloc((size_t)8*16384*2);
  if (off > ws_size) return;

  // CSR build
  hipMemsetAsync(counts, 0, (size_t)E*4, stream);
  hist_kernel<<<2048, 256, 0, stream>>>(id_ji, counts, T);
  blocksum_kernel<<<nSeg, 256, 0, stream>>>(counts, partial, E);
  scanpart_kernel<<<1, 256, 0, stream>>>(partial, nSeg);
  scatter_kernel<<<nSeg, 256, 0, stream>>>(counts, partial, offs, cursor, E, T);
  fill_kernel<<<2048, 256, 0, stream>>>(id_ji, id_kj, cursor, pkj, ppos, T);

  // weight preps
  Ptrs9 p9;
  p9.p[0] = W_ji;  p9.p[1] = W_kj;  p9.p[2] = r1_W1; p9.p[3] = r1_W2; p9.p[4] = W_bs;
  p9.p[5] = r3_W1; p9.p[6] = r3_W2; p9.p[7] = r4_W1; p9.p[8] = r4_W2;
  prep_w_kernel<<<dim3(64, 9), 256, 0, stream>>>(p9, Wbt);
  prep_bilin_kernel<<<512, 256, 0, stream>>>(bilin, WtB);
  a_pre_kernel<<<(T + 255)/256, 256, 0, stream>>>(a_sbf, W_sbf, ppos, apg, T);

  head_kernel<<<nTiles, 512, 0, stream>>>(m_l_1, Wbt + 0*16384, Wbt + 1*16384,
                                          b_ji, b_kj, e_rbf, W_rbf,
                                          mji, mkj, mlbf, E);
  ygemm_kernel<<<dim3(nTiles, 8), 256, 0, stream>>>(mkj, WtB, Y);
  stage2_kernel<0><<<(E + 3)/4, 256, 0, stream>>>(offs, pkj, apg, Y, mji, h0, E);
  stage2_kernel<1><<<(E + 3)/4, 256, 0, stream>>>(offs, pkj, apg, Y, mji, h0, E);

  Bias7 bz;
  bz.p[0] = r1_b1; bz.p[1] = r1_b2; bz.p[2] = b_bs;
  bz.p[3] = r3_b1; bz.p[4] = r3_b2; bz.p[5] = r4_b1; bz.p[6] = r4_b2;
  chain_kernel<<<nTiles, 512, 0, stream>>>(h0, mlbf, Wbt, bz, (float*)d_out, E);
}

// Round 6
// 1008.853 us; speedup vs baseline: 1.8166x; 1.0944x over previous
//
#include <hip/hip_runtime.h>
#include <hip/hip_bf16.h>

#define F 128
#define NRAD 6
#define NSPH 42

typedef __attribute__((ext_vector_type(8))) short bf16x8;
typedef __attribute__((ext_vector_type(4))) float f32x4;

__device__ __forceinline__ float bflo(unsigned int v){ return __uint_as_float(v << 16); }
__device__ __forceinline__ float bfhi(unsigned int v){ return __uint_as_float(v & 0xFFFF0000u); }
__device__ __forceinline__ unsigned short f2bf(float f){
  unsigned int u = __float_as_uint(f);
  return (unsigned short)((u + 0x7FFFu + ((u >> 16) & 1u)) >> 16);
}
__device__ __forceinline__ float bf2f(unsigned short u){ return __uint_as_float(((unsigned int)u) << 16); }
__device__ __forceinline__ unsigned int pack2bf(float a, float b){
  return (unsigned int)f2bf(a) | ((unsigned int)f2bf(b) << 16);
}
__device__ __forceinline__ float swishf(float x){ return x / (1.f + __expf(-x)); }

// ---------------- CSR build ----------------
__global__ void hist_kernel(const int* __restrict__ id_ji, int* __restrict__ counts, int T){
  for (int i = blockIdx.x*blockDim.x + threadIdx.x; i < T; i += gridDim.x*blockDim.x)
    atomicAdd(&counts[id_ji[i]], 1);
}

// coalesced 2-level scan: blocksum -> scanpart -> scatter
__global__ __launch_bounds__(256) void blocksum_kernel(const int* __restrict__ counts,
    int* __restrict__ partial, int E){
  int base = blockIdx.x*1024;
  int tid = threadIdx.x;
  int s = 0;
  #pragma unroll
  for (int it = 0; it < 4; ++it){
    int i = base + tid + it*256;
    if (i < E) s += counts[i];
  }
  #pragma unroll
  for (int d = 1; d < 64; d <<= 1) s += __shfl_xor(s, d);
  __shared__ int ws[4];
  if ((tid & 63) == 0) ws[tid >> 6] = s;
  __syncthreads();
  if (tid == 0) partial[blockIdx.x] = ws[0] + ws[1] + ws[2] + ws[3];
}

__global__ __launch_bounds__(256) void scanpart_kernel(int* __restrict__ partial, int nb){
  __shared__ int sh[1024];
  int tid = threadIdx.x;
  for (int i = tid; i < nb; i += 256) sh[i] = partial[i];
  __syncthreads();
  if (tid == 0){
    int run = 0;
    for (int i = 0; i < nb; ++i){ int c = sh[i]; sh[i] = run; run += c; }
  }
  __syncthreads();
  for (int i = tid; i < nb; i += 256) partial[i] = sh[i];
}

__global__ __launch_bounds__(256) void scatter_kernel(const int* __restrict__ counts,
    const int* __restrict__ partial, int* __restrict__ offs, int* __restrict__ cursor,
    int E, int T){
  int base = blockIdx.x*1024;
  int tid = threadIdx.x;
  int i0 = base + tid*4;
  int4 c4 = make_int4(0,0,0,0);
  if (i0 + 3 < E) c4 = *(const int4*)(counts + i0);
  else {
    if (i0   < E) c4.x = counts[i0];
    if (i0+1 < E) c4.y = counts[i0+1];
    if (i0+2 < E) c4.z = counts[i0+2];
    if (i0+3 < E) c4.w = counts[i0+3];
  }
  int tsum = c4.x + c4.y + c4.z + c4.w;
  int lane = tid & 63, w = tid >> 6;
  int v = tsum;
  #pragma unroll
  for (int d = 1; d < 64; d <<= 1){ int t = __shfl_up(v, d); if (lane >= d) v += t; }
  __shared__ int ws[4];
  if (lane == 63) ws[w] = v;
  __syncthreads();
  int wb = 0;
  #pragma unroll
  for (int k = 0; k < 4; ++k) if (k < w) wb += ws[k];
  int run = partial[blockIdx.x] + wb + (v - tsum);
  int o0 = run;
  int o1 = o0 + c4.x;
  int o2 = o1 + c4.y;
  int o3 = o2 + c4.z;
  int4 o = make_int4(o0, o1, o2, o3);
  if (i0 + 3 < E){
    *(int4*)(offs + i0) = o;
    *(int4*)(cursor + i0) = o;
  } else {
    if (i0   < E){ offs[i0]   = o0; cursor[i0]   = o0; }
    if (i0+1 < E){ offs[i0+1] = o1; cursor[i0+1] = o1; }
    if (i0+2 < E){ offs[i0+2] = o2; cursor[i0+2] = o2; }
    if (i0+3 < E){ offs[i0+3] = o3; cursor[i0+3] = o3; }
  }
  if (blockIdx.x == 0 && tid == 0) offs[E] = T;
}

// fill: pkj[pos] = id_kj[i]; ppos[i] = pos (inverse perm for a_pre scatter)
__global__ void fill_kernel(const int* __restrict__ id_ji, const int* __restrict__ id_kj,
                            int* __restrict__ cursor, int* __restrict__ pkj,
                            int* __restrict__ ppos, int T){
  for (int i = blockIdx.x*blockDim.x + threadIdx.x; i < T; i += gridDim.x*blockDim.x){
    int pos = atomicAdd(&cursor[id_ji[i]], 1);
    pkj[pos] = id_kj[i];
    ppos[i] = pos;
  }
}

// ---------------- weight prep (pre-swizzled LDS-image layouts) ----------------
struct Ptrs9 { const float* p[9]; };

// Bt[n][k] = W[k][n], stored as swizzled image: dst[n*128 + (k ^ ((n&7)<<3))]
__global__ void prep_w_kernel(Ptrs9 ps, unsigned short* __restrict__ dst){
  int i = blockIdx.y;
  const float* src = ps.p[i];
  int idx = blockIdx.x*256 + threadIdx.x;     // 0..16383
  int n = idx >> 7, k = idx & 127;
  dst[i*16384 + n*128 + (k ^ ((n & 7) << 3))] = f2bf(src[k*128 + n]);
}

// WtB image: row n = j*128+i (tile j, within-tile row i), col l; value bilin[i][j][l]
__global__ void prep_bilin_kernel(const float* __restrict__ bilin, unsigned short* __restrict__ dst){
  int t = blockIdx.x*256 + threadIdx.x;       // 0..131071
  int n = t >> 7, l = t & 127;
  int i = n & 127, j = n >> 7;
  int r = n & 127;
  dst[(size_t)n*128 + (l ^ ((r & 7) << 3))] = f2bf(bilin[(size_t)i*1024 + j*128 + l]);
}

// a8 = a_sbf @ W_sbf, scattered directly into perm order via ppos
// float4-vectorized staging into LINEAR LDS image (block segment is 16B-aligned:
// 256 rows * 42 floats * 4B = 43008 B per block).
__global__ __launch_bounds__(256) void a_pre_kernel(const float* __restrict__ a_sbf,
    const float* __restrict__ W_sbf, const int* __restrict__ ppos,
    uint4* __restrict__ apg, int T){
  __shared__ float tile[256*NSPH];
  __shared__ float wsh[NSPH*8];
  int tid = threadIdx.x;
  int w0 = blockIdx.x*256;
  for (int i = tid; i < NSPH*8; i += 256) wsh[i] = W_sbf[i];
  int rows = min(256, T - w0);
  int fl = rows * NSPH;
  int nf4 = fl >> 2;
  const float4* src4 = (const float4*)(a_sbf + (size_t)w0 * NSPH);
  float4* dst4 = (float4*)tile;
  for (int i = tid; i < nf4; i += 256) dst4[i] = src4[i];
  for (int i = (nf4 << 2) + tid; i < fl; i += 256) tile[i] = a_sbf[(size_t)w0*NSPH + i];
  __syncthreads();
  if (tid >= rows) return;
  float out[8] = {0,0,0,0,0,0,0,0};
  const float* row = &tile[tid*NSPH];
  #pragma unroll 6
  for (int s = 0; s < NSPH; ++s){
    float av = row[s];
    #pragma unroll
    for (int j = 0; j < 8; ++j) out[j] += av * wsh[s*8 + j];
  }
  uint4 ov;
  ov.x = pack2bf(out[0], out[1]);
  ov.y = pack2bf(out[2], out[3]);
  ov.z = pack2bf(out[4], out[5]);
  ov.w = pack2bf(out[6], out[7]);
  apg[ppos[w0 + tid]] = ov;
}

// ---------------- shared MFMA helper ----------------
template<int MR, int NR>
__device__ __forceinline__ void mfma_kloop(
    const unsigned short (*As)[128], const unsigned short (*Ws)[128],
    int wr, int wc, int lrow, int lk, f32x4 acc[MR][NR]){
  #pragma unroll
  for (int m = 0; m < MR; ++m)
    #pragma unroll
    for (int n = 0; n < NR; ++n)
      acc[m][n] = (f32x4){0.f,0.f,0.f,0.f};
  #pragma unroll
  for (int k = 0; k < 4; ++k){
    bf16x8 af[MR], bf[NR];
    #pragma unroll
    for (int m = 0; m < MR; ++m){
      int r = wr + m*16 + lrow;
      int c = (k*32 + lk) ^ ((r & 7) << 3);
      af[m] = *(const bf16x8*)(&As[r][c]);
    }
    #pragma unroll
    for (int n = 0; n < NR; ++n){
      int r = wc + n*16 + lrow;
      int c = (k*32 + lk) ^ ((r & 7) << 3);
      bf[n] = *(const bf16x8*)(&Ws[r][c]);
    }
    #pragma unroll
    for (int m = 0; m < MR; ++m)
      #pragma unroll
      for (int n = 0; n < NR; ++n)
        acc[m][n] = __builtin_amdgcn_mfma_f32_16x16x32_bf16(af[m], bf[n], acc[m][n], 0, 0, 0);
  }
}

// ---------------- head: m_ji, m_kj (gated), mlbf in one pass (512 thr) ----------------
__global__ __launch_bounds__(512) void head_kernel(
    const float* __restrict__ A, const unsigned short* __restrict__ Wji,
    const unsigned short* __restrict__ Wkj,
    const float* __restrict__ b_ji, const float* __restrict__ b_kj,
    const float* __restrict__ e_rbf, const float* __restrict__ W_rbf,
    unsigned short* __restrict__ m_ji, unsigned short* __restrict__ m_kj,
    unsigned short* __restrict__ mlbf, int E){
  __shared__ unsigned short Hs[128][128];
  __shared__ unsigned short W1s[128][128];
  __shared__ unsigned short W2s[128][128];
  int tid = threadIdx.x;
  int row0 = blockIdx.x * 128;
  #pragma unroll
  for (int it = 0; it < 8; ++it){
    int lin = tid + it*512;
    int r = lin >> 5;
    int c = (lin & 31) * 4;
    float4 v = make_float4(0.f,0.f,0.f,0.f);
    bool ok = (row0 + r < E);
    if (ok) v = *(const float4*)(A + (size_t)(row0 + r)*128 + c);
    uint2 o; o.x = pack2bf(v.x, v.y); o.y = pack2bf(v.z, v.w);
    int cs = c ^ ((r & 7) << 3);
    *(uint2*)(&Hs[r][cs]) = o;
    if (ok) *(uint2*)(mlbf + (size_t)(row0 + r)*128 + cs) = o;
  }
  #pragma unroll
  for (int it = 0; it < 4; ++it){
    int lin = tid + it*512;
    ((uint4*)W1s)[lin] = ((const uint4*)Wji)[lin];
    ((uint4*)W2s)[lin] = ((const uint4*)Wkj)[lin];
  }
  __syncthreads();
  int wid = tid >> 6, lane = tid & 63;
  int wr = (wid >> 2)*64, wc = (wid & 3)*32;
  int lrow = lane & 15, lk = (lane >> 4)*8;
  f32x4 acc1[4][2], acc2[4][2];
  #pragma unroll
  for (int m = 0; m < 4; ++m)
    #pragma unroll
    for (int n = 0; n < 2; ++n){ acc1[m][n] = (f32x4){0,0,0,0}; acc2[m][n] = (f32x4){0,0,0,0}; }
  #pragma unroll
  for (int k = 0; k < 4; ++k){
    bf16x8 af[4], b1[2], b2[2];
    #pragma unroll
    for (int m = 0; m < 4; ++m){
      int r = wr + m*16 + lrow;
      int c = (k*32 + lk) ^ ((r & 7) << 3);
      af[m] = *(const bf16x8*)(&Hs[r][c]);
    }
    #pragma unroll
    for (int n = 0; n < 2; ++n){
      int r = wc + n*16 + lrow;
      int c = (k*32 + lk) ^ ((r & 7) << 3);
      b1[n] = *(const bf16x8*)(&W1s[r][c]);
      b2[n] = *(const bf16x8*)(&W2s[r][c]);
    }
    #pragma unroll
    for (int m = 0; m < 4; ++m)
      #pragma unroll
      for (int n = 0; n < 2; ++n){
        acc1[m][n] = __builtin_amdgcn_mfma_f32_16x16x32_bf16(af[m], b1[n], acc1[m][n], 0, 0, 0);
        acc2[m][n] = __builtin_amdgcn_mfma_f32_16x16x32_bf16(af[m], b2[n], acc2[m][n], 0, 0, 0);
      }
  }
  __syncthreads();
  int drow0 = (lane >> 4)*4, dcol = lane & 15;
  // ---- m_ji = swish(acc1 + b_ji) ----
  #pragma unroll
  for (int m = 0; m < 4; ++m)
    #pragma unroll
    for (int n = 0; n < 2; ++n){
      int col = wc + n*16 + dcol;
      float bv = b_ji[col];
      #pragma unroll
      for (int q = 0; q < 4; ++q){
        int r = wr + m*16 + drow0 + q;
        Hs[r][col ^ ((r & 7) << 3)] = f2bf(swishf(acc1[m][n][q] + bv));
      }
    }
  __syncthreads();
  #pragma unroll
  for (int it = 0; it < 4; ++it){
    int lin = tid + it*512;
    int r = lin >> 4; int c = (lin & 15)*8;
    uint4 d = *(const uint4*)(&Hs[r][c ^ ((r & 7) << 3)]);
    if (row0 + r < E) *(uint4*)(m_ji + (size_t)(row0 + r)*128 + c) = d;
  }
  __syncthreads();
  // ---- m_kj = swish(acc2 + b_kj) * (e_rbf @ W_rbf), stored as swizzled image ----
  float wrb[2][6];
  #pragma unroll
  for (int n = 0; n < 2; ++n){
    int col = wc + n*16 + dcol;
    #pragma unroll
    for (int rr = 0; rr < 6; ++rr) wrb[n][rr] = W_rbf[rr*128 + col];
  }
  #pragma unroll
  for (int m = 0; m < 4; ++m){
    #pragma unroll
    for (int q = 0; q < 4; ++q){
      int grow = row0 + wr + m*16 + drow0 + q;
      int er = (grow < E) ? grow : 0;
      float e0 = e_rbf[er*6+0], e1 = e_rbf[er*6+1], e2 = e_rbf[er*6+2];
      float e3 = e_rbf[er*6+3], e4 = e_rbf[er*6+4], e5 = e_rbf[er*6+5];
      int rloc = wr + m*16 + drow0 + q;
      #pragma unroll
      for (int n = 0; n < 2; ++n){
        int col = wc + n*16 + dcol;
        float g = e0*wrb[n][0] + e1*wrb[n][1] + e2*wrb[n][2]
                + e3*wrb[n][3] + e4*wrb[n][4] + e5*wrb[n][5];
        float v = swishf(acc2[m][n][q] + b_kj[col]) * g;
        Hs[rloc][col ^ ((rloc & 7) << 3)] = f2bf(v);
      }
    }
  }
  __syncthreads();
  #pragma unroll
  for (int it = 0; it < 4; ++it){
    int lin = tid + it*512;
    int r = lin >> 4;
    if (row0 + r < E)
      ((uint4*)(m_kj + (size_t)row0*128))[lin] = ((const uint4*)Hs)[lin];
  }
}

// ---------------- Y = m_kj @ bilin^T  [Epad,1024] ----------------
__global__ __launch_bounds__(256) void ygemm_kernel(
    const unsigned short* __restrict__ Aimg, const unsigned short* __restrict__ Bimg,
    unsigned short* __restrict__ Y){
  __shared__ unsigned short As[128][128];
  __shared__ unsigned short Bs[128][128];
  int tid = threadIdx.x;
  int row0 = blockIdx.x*128, bn = blockIdx.y;
  #pragma unroll
  for (int it = 0; it < 8; ++it){
    int lin = tid + it*256;
    ((uint4*)As)[lin] = ((const uint4*)(Aimg + (size_t)row0*128))[lin];
    ((uint4*)Bs)[lin] = ((const uint4*)(Bimg + (size_t)bn*16384))[lin];
  }
  __syncthreads();
  int wid = tid >> 6, lane = tid & 63;
  int wr = (wid >> 1)*64, wc = (wid & 1)*64;
  int lrow = lane & 15, lk = (lane >> 4)*8;
  f32x4 acc[4][4];
  mfma_kloop<4,4>(As, Bs, wr, wc, lrow, lk, acc);
  __syncthreads();
  int drow0 = (lane >> 4)*4, dcol = lane & 15;
  #pragma unroll
  for (int m = 0; m < 4; ++m)
    #pragma unroll
    for (int n = 0; n < 4; ++n)
      #pragma unroll
      for (int q = 0; q < 4; ++q){
        int r = wr + m*16 + drow0 + q;
        int col = wc + n*16 + dcol;
        As[r][col ^ ((r & 7) << 3)] = f2bf(acc[m][n][q]);
      }
  __syncthreads();
  #pragma unroll
  for (int it = 0; it < 8; ++it){
    int lin = tid + it*256;
    int r = lin >> 4; int c = (lin & 15)*8;
    uint4 d = *(const uint4*)(&As[r][c ^ ((r & 7) << 3)]);
    *(uint4*)(Y + (size_t)(row0 + r)*1024 + bn*128 + c) = d;
  }
}

// ---------------- stage 2: per-edge gather-reduce, j-half split ----------------
// PASS 0: cols j=0..3 (first half of Y rows), partial -> h0img (bf16, plain rows)
// PASS 1: cols j=4..7, add partial + m_ji, write swizzled h0 image in place
template<int PASS>
__global__ __launch_bounds__(256) void stage2_kernel(
    const int* __restrict__ offs, const int* __restrict__ pkj,
    const uint4* __restrict__ apg, const unsigned short* __restrict__ Y,
    const unsigned short* __restrict__ m_ji, unsigned short* __restrict__ h0img, int E){
  int e = blockIdx.x*4 + (threadIdx.x >> 6);
  if (e >= E) return;
  int lane = threadIdx.x & 63;
  int jsel = lane >> 4;
  int beg = offs[e], end = offs[e+1];
  float acc[8] = {0,0,0,0,0,0,0,0};
  int kj = 0; uint4 av = make_uint4(0,0,0,0);
  if (beg < end){ kj = pkj[beg]; av = apg[beg]; }
  for (int idx = beg; idx < end; ++idx){
    const uint4* yrow = (const uint4*)(Y + (size_t)kj*1024);
    uint4 y = (PASS == 0) ? yrow[lane] : yrow[64 + lane];
    int kjn = kj; uint4 avn = av;
    if (idx + 1 < end){ kjn = pkj[idx+1]; avn = apg[idx+1]; }
    unsigned int u;
    if (PASS == 0) u = (jsel & 2) ? av.y : av.x;
    else           u = (jsel & 2) ? av.w : av.z;
    float a = (jsel & 1) ? bfhi(u) : bflo(u);
    acc[0] += a*bflo(y.x); acc[1] += a*bfhi(y.x);
    acc[2] += a*bflo(y.y); acc[3] += a*bfhi(y.y);
    acc[4] += a*bflo(y.z); acc[5] += a*bfhi(y.z);
    acc[6] += a*bflo(y.w); acc[7] += a*bfhi(y.w);
    kj = kjn; av = avn;
  }
  #pragma unroll
  for (int q = 0; q < 8; ++q){
    acc[q] += __shfl_xor(acc[q], 16);
    acc[q] += __shfl_xor(acc[q], 32);
  }
  if (lane < 16){
    if (PASS == 0){
      uint4 o;
      o.x = pack2bf(acc[0], acc[1]); o.y = pack2bf(acc[2], acc[3]);
      o.z = pack2bf(acc[4], acc[5]); o.w = pack2bf(acc[6], acc[7]);
      ((uint4*)(h0img + (size_t)e*128))[lane] = o;           // plain partial
    } else {
      uint4 xp = ((const uint4*)(h0img + (size_t)e*128))[lane];
      acc[0] += bflo(xp.x); acc[1] += bfhi(xp.x);
      acc[2] += bflo(xp.y); acc[3] += bfhi(xp.y);
      acc[4] += bflo(xp.z); acc[5] += bfhi(xp.z);
      acc[6] += bflo(xp.w); acc[7] += bfhi(xp.w);
      uint4 mj = ((const uint4*)(m_ji + (size_t)e*128))[lane];
      acc[0] += bflo(mj.x); acc[1] += bfhi(mj.x);
      acc[2] += bflo(mj.y); acc[3] += bfhi(mj.y);
      acc[4] += bflo(mj.z); acc[5] += bfhi(mj.z);
      acc[6] += bflo(mj.w); acc[7] += bfhi(mj.w);
      uint4 o;
      o.x = pack2bf(acc[0], acc[1]); o.y = pack2bf(acc[2], acc[3]);
      o.z = pack2bf(acc[4], acc[5]); o.w = pack2bf(acc[6], acc[7]);
      ((uint4*)(h0img + (size_t)e*128))[lane ^ (e & 7)] = o; // swizzled image
    }
  }
}

// ---------------- fused residual chain: 7 GEMMs, state in LDS (512 thr) ----------------
struct Bias7 { const float* p[7]; };

__global__ __launch_bounds__(512) void chain_kernel(
    const unsigned short* __restrict__ h0img, const unsigned short* __restrict__ mlimg,
    const unsigned short* __restrict__ Wimg, Bias7 bz, float* __restrict__ out, int E){
  __shared__ unsigned short HA[128][128];
  __shared__ unsigned short HB[128][128];
  __shared__ unsigned short W0[128][128];
  __shared__ unsigned short W1[128][128];
  int tid = threadIdx.x;
  int row0 = blockIdx.x * 128;
  #pragma unroll
  for (int it = 0; it < 4; ++it){
    int lin = tid + it*512;
    ((uint4*)HA)[lin] = ((const uint4*)(h0img + (size_t)row0*128))[lin];
    ((uint4*)W0)[lin] = ((const uint4*)(Wimg + 2*16384))[lin];
  }
  __syncthreads();
  int wid = tid >> 6, lane = tid & 63;
  int wr = (wid >> 2)*64, wc = (wid & 3)*32;
  int lrow = lane & 15, lk = (lane >> 4)*8;
  int drow0 = (lane >> 4)*4, dcol = lane & 15;
  f32x4 acc[4][2];
  unsigned int R[4][2][2];
  float bc[2];

  auto stageW = [&](unsigned short (*dst)[128], int tile){
    #pragma unroll
    for (int it = 0; it < 4; ++it){
      int lin = tid + it*512;
      ((uint4*)dst)[lin] = ((const uint4*)(Wimg + (size_t)tile*16384))[lin];
    }
  };
  auto getb = [&](const float* b){
    #pragma unroll
    for (int n = 0; n < 2; ++n) bc[n] = b[wc + n*16 + dcol];
  };
  auto wstate = [&](unsigned short (*dst)[128], int m, int n, int q, float v){
    int r = wr + m*16 + drow0 + q, c = wc + n*16 + dcol;
    dst[r][c ^ ((r & 7) << 3)] = f2bf(v);
  };
  auto rstate = [&](const unsigned short (*src)[128], int m, int n, int q)->float{
    int r = wr + m*16 + drow0 + q, c = wc + n*16 + dcol;
    return bf2f(src[r][c ^ ((r & 7) << 3)]);
  };

  // s1: h1 = sw(h0 @ r1W1 + b) -> HB
  mfma_kloop<4,2>(HA, W0, wr, wc, lrow, lk, acc);
  getb(bz.p[0]);
  stageW(W1, 3);
  #pragma unroll
  for (int m = 0; m < 4; ++m)
    #pragma unroll
    for (int n = 0; n < 2; ++n)
      #pragma unroll
      for (int q = 0; q < 4; ++q)
        wstate(HB, m, n, q, swishf(acc[m][n][q] + bc[n]));
  __syncthreads();

  // s2: h2 = h0 + sw(h1 @ r1W2 + b) -> HB ; ml -> HA
  mfma_kloop<4,2>(HB, W1, wr, wc, lrow, lk, acc);
  getb(bz.p[1]);
  __syncthreads();                       // done reading HB
  float h0v[4][2][4];
  #pragma unroll
  for (int m = 0; m < 4; ++m)
    #pragma unroll
    for (int n = 0; n < 2; ++n)
      #pragma unroll
      for (int q = 0; q < 4; ++q)
        h0v[m][n][q] = rstate(HA, m, n, q);
  __syncthreads();                       // done reading HA (h0)
  stageW(W0, 4);
  #pragma unroll
  for (int it = 0; it < 4; ++it){
    int lin = tid + it*512;
    ((uint4*)HA)[lin] = ((const uint4*)(mlimg + (size_t)row0*128))[lin];
  }
  #pragma unroll
  for (int m = 0; m < 4; ++m)
    #pragma unroll
    for (int n = 0; n < 2; ++n)
      #pragma unroll
      for (int q = 0; q < 4; ++q)
        wstate(HB, m, n, q, h0v[m][n][q] + swishf(acc[m][n][q] + bc[n]));
  __syncthreads();

  // s3: h3 = sw(h2 @ Wbs + b) + ml -> HB ; R = h3
  mfma_kloop<4,2>(HB, W0, wr, wc, lrow, lk, acc);
  getb(bz.p[2]);
  __syncthreads();                       // done reading HB
  stageW(W1, 5);
  #pragma unroll
  for (int m = 0; m < 4; ++m)
    #pragma unroll
    for (int n = 0; n < 2; ++n){
      float v[4];
      #pragma unroll
      for (int q = 0; q < 4; ++q){
        v[q] = swishf(acc[m][n][q] + bc[n]) + rstate(HA, m, n, q);
        wstate(HB, m, n, q, v[q]);
      }
      R[m][n][0] = pack2bf(v[0], v[1]);
      R[m][n][1] = pack2bf(v[2], v[3]);
    }
  __syncthreads();

  // s4: h4 = sw(h3 @ r3W1 + b) -> HA
  mfma_kloop<4,2>(HB, W1, wr, wc, lrow, lk, acc);
  getb(bz.p[3]);
  stageW(W0, 6);
  #pragma unroll
  for (int m = 0; m < 4; ++m)
    #pragma unroll
    for (int n = 0; n < 2; ++n)
      #pragma unroll
      for (int q = 0; q < 4; ++q)
        wstate(HA, m, n, q, swishf(acc[m][n][q] + bc[n]));
  __syncthreads();

  // s5: h5 = h3 + sw(h4 @ r3W2 + b) -> HB ; R = h5
  mfma_kloop<4,2>(HA, W0, wr, wc, lrow, lk, acc);
  getb(bz.p[4]);
  stageW(W1, 7);
  #pragma unroll
  for (int m = 0; m < 4; ++m)
    #pragma unroll
    for (int n = 0; n < 2; ++n){
      float v[4];
      #pragma unroll
      for (int q = 0; q < 4; ++q){
        unsigned int u = R[m][n][q >> 1];
        float rv = (q & 1) ? bfhi(u) : bflo(u);
        v[q] = rv + swishf(acc[m][n][q] + bc[n]);
        wstate(HB, m, n, q, v[q]);
      }
      R[m][n][0] = pack2bf(v[0], v[1]);
      R[m][n][1] = pack2bf(v[2], v[3]);
    }
  __syncthreads();

  // s6: h6 = sw(h5 @ r4W1 + b) -> HA
  mfma_kloop<4,2>(HB, W1, wr, wc, lrow, lk, acc);
  getb(bz.p[5]);
  stageW(W0, 8);
  #pragma unroll
  for (int m = 0; m < 4; ++m)
    #pragma unroll
    for (int n = 0; n < 2; ++n)
      #pragma unroll
      for (int q = 0; q < 4; ++q)
        wstate(HA, m, n, q, swishf(acc[m][n][q] + bc[n]));
  __syncthreads();

  // s7: out = h5 + sw(h6 @ r4W2 + b)  (f32 global)
  mfma_kloop<4,2>(HA, W0, wr, wc, lrow, lk, acc);
  getb(bz.p[6]);
  #pragma unroll
  for (int m = 0; m < 4; ++m)
    #pragma unroll
    for (int n = 0; n < 2; ++n){
      int col = wc + n*16 + dcol;
      #pragma unroll
      for (int q = 0; q < 4; ++q){
        int grow = row0 + wr + m*16 + drow0 + q;
        if (grow < E){
          unsigned int u = R[m][n][q >> 1];
          float rv = (q & 1) ? bfhi(u) : bflo(u);
          out[(size_t)grow*128 + col] = rv + swishf(acc[m][n][q] + bc[n]);
        }
      }
    }
}

// ---------------- host ----------------
extern "C" void kernel_launch(void* const* d_in, const int* in_sizes, int n_in,
                              void* d_out, int out_size, void* d_ws, size_t ws_size,
                              hipStream_t stream){
  const float* m_l_1 = (const float*)d_in[0];
  const float* e_rbf = (const float*)d_in[1];
  const float* a_sbf = (const float*)d_in[2];
  const int* id_kj   = (const int*)d_in[3];
  const int* id_ji   = (const int*)d_in[4];
  const float* W_rbf = (const float*)d_in[5];
  const float* W_sbf = (const float*)d_in[6];
  const float* W_ji  = (const float*)d_in[7];
  const float* b_ji  = (const float*)d_in[8];
  const float* W_kj  = (const float*)d_in[9];
  const float* b_kj  = (const float*)d_in[10];
  const float* bilin = (const float*)d_in[11];
  const float* W_bs  = (const float*)d_in[12];
  const float* b_bs  = (const float*)d_in[13];
  const float* r1_W1 = (const float*)d_in[14]; const float* r1_b1 = (const float*)d_in[15];
  const float* r1_W2 = (const float*)d_in[16]; const float* r1_b2 = (const float*)d_in[17];
  const float* r3_W1 = (const float*)d_in[18]; const float* r3_b1 = (const float*)d_in[19];
  const float* r3_W2 = (const float*)d_in[20]; const float* r3_b2 = (const float*)d_in[21];
  const float* r4_W1 = (const float*)d_in[22]; const float* r4_b1 = (const float*)d_in[23];
  const float* r4_W2 = (const float*)d_in[24]; const float* r4_b2 = (const float*)d_in[25];

  const int E = in_sizes[0] / F;
  const int T = in_sizes[3];
  const int nTiles = (E + 127) / 128;
  const int Epad = nTiles * 128;
  const int nSeg = (E + 1023) / 1024;

  char* ws = (char*)d_ws;
  size_t off = 0;
  auto alloc = [&](size_t b)->char*{
    char* p = ws + off;
    off = (off + b + 255) & ~(size_t)255;
    return p;
  };
  unsigned short* Y    = (unsigned short*)alloc((size_t)Epad*1024*2);
  unsigned short* mji  = (unsigned short*)alloc((size_t)Epad*F*2);
  unsigned short* mkj  = (unsigned short*)alloc((size_t)Epad*F*2);
  unsigned short* h0   = (unsigned short*)alloc((size_t)Epad*F*2);
  unsigned short* mlbf = (unsigned short*)alloc((size_t)Epad*F*2);
  uint4* apg  = (uint4*)alloc((size_t)T*16);
  int* pkj    = (int*)alloc((size_t)T*4);
  int* ppos   = (int*)alloc((size_t)T*4);
  int* counts = (int*)alloc((size_t)E*4);
  int* offs   = (int*)alloc((size_t)(E+1)*4);
  int* cursor = (int*)alloc((size_t)E*4);
  int* partial= (int*)alloc((size_t)(nSeg+1)*4);
  unsigned short* Wbt = (unsigned short*)alloc((size_t)9*16384*2);
  unsigned short* WtB = (unsigned short*)alloc((size_t)8*16384*2);
  if (off > ws_size) return;

  // CSR build
  hipMemsetAsync(counts, 0, (size_t)E*4, stream);
  hist_kernel<<<2048, 256, 0, stream>>>(id_ji, counts, T);
  blocksum_kernel<<<nSeg, 256, 0, stream>>>(counts, partial, E);
  scanpart_kernel<<<1, 256, 0, stream>>>(partial, nSeg);
  scatter_kernel<<<nSeg, 256, 0, stream>>>(counts, partial, offs, cursor, E, T);
  fill_kernel<<<2048, 256, 0, stream>>>(id_ji, id_kj, cursor, pkj, ppos, T);

  // weight preps
  Ptrs9 p9;
  p9.p[0] = W_ji;  p9.p[1] = W_kj;  p9.p[2] = r1_W1; p9.p[3] = r1_W2; p9.p[4] = W_bs;
  p9.p[5] = r3_W1; p9.p[6] = r3_W2; p9.p[7] = r4_W1; p9.p[8] = r4_W2;
  prep_w_kernel<<<dim3(64, 9), 256, 0, stream>>>(p9, Wbt);
  prep_bilin_kernel<<<512, 256, 0, stream>>>(bilin, WtB);
  a_pre_kernel<<<(T + 255)/256, 256, 0, stream>>>(a_sbf, W_sbf, ppos, apg, T);

  head_kernel<<<nTiles, 512, 0, stream>>>(m_l_1, Wbt + 0*16384, Wbt + 1*16384,
                                          b_ji, b_kj, e_rbf, W_rbf,
                                          mji, mkj, mlbf, E);
  ygemm_kernel<<<dim3(nTiles, 8), 256, 0, stream>>>(mkj, WtB, Y);
  stage2_kernel<0><<<(E + 3)/4, 256, 0, stream>>>(offs, pkj, apg, Y, mji, h0, E);
  stage2_kernel<1><<<(E + 3)/4, 256, 0, stream>>>(offs, pkj, apg, Y, mji, h0, E);

  Bias7 bz;
  bz.p[0] = r1_b1; bz.p[1] = r1_b2; bz.p[2] = b_bs;
  bz.p[3] = r3_b1; bz.p[4] = r3_b2; bz.p[5] = r4_b1; bz.p[6] = r4_b2;
  chain_kernel<<<nTiles, 512, 0, stream>>>(h0, mlbf, Wbt, bz, (float*)d_out, E);
}